// Round 19
// baseline (217.900 us; speedup 1.0000x reference)
//
#include <hip/hip_runtime.h>

#define Bq 8
#define Tq 64
#define Sq 256
#define Hq 768
#define TT 8
#define ST 16

typedef float f32x4 __attribute__((ext_vector_type(4)));
typedef __bf16 bf16x8 __attribute__((ext_vector_type(8)));

#define TANH_SCALE 2.885390081777927f   // 2*log2(e): exp2(u*TS) = e^{2u}
#define LOG2E 1.4426950408889634f

// ---- DPP wave reduction -----------------------------------------------------
template <int Ctrl, int Rmask>
__device__ __forceinline__ float dpp_add_f(float v) {
  int t = __builtin_amdgcn_update_dpp(0, __float_as_int(v), Ctrl, Rmask, 0xF, true);
  return v + __int_as_float(t);
}
__device__ __forceinline__ float wave64_sum(float v) {
  v = dpp_add_f<0xB1, 0xF>(v);
  v = dpp_add_f<0x4E, 0xF>(v);
  v = dpp_add_f<0x141, 0xF>(v);
  v = dpp_add_f<0x140, 0xF>(v);
  v = dpp_add_f<0x142, 0xA>(v);
  v = dpp_add_f<0x143, 0xC>(v);
  return __int_as_float(__builtin_amdgcn_readlane(__float_as_int(v), 63));
}

__device__ __forceinline__ bf16x8 cvt8(f32x4 lo, f32x4 hi) {
  bf16x8 t;
  t[0] = (__bf16)lo[0]; t[1] = (__bf16)lo[1]; t[2] = (__bf16)lo[2]; t[3] = (__bf16)lo[3];
  t[4] = (__bf16)hi[0]; t[5] = (__bf16)hi[1]; t[6] = (__bf16)hi[2]; t[7] = (__bf16)hi[3];
  return t;
}

// ---------------- projection GEMMs (LDS-staged, double-buffered) --------------
// Stores PRE-EXPONENTIATED outputs E=exp2(TS*ef), D=exp2(TS*dec) as bf16.
// Side duty: w1 = v*wc stream, zero lacc + sync counters/flags.
__global__ __launch_bounds__(256, 4) void proj_kernel(
    const float* __restrict__ enc, const float* __restrict__ dec,
    const float* __restrict__ Wh, const float* __restrict__ Wd,
    const float* __restrict__ bd,
    const float* __restrict__ wcvec, const float* __restrict__ vvec,
    __bf16* __restrict__ efh, __bf16* __restrict__ decfh,
    float* __restrict__ w1g, float* __restrict__ lacc,
    unsigned* __restrict__ cnt, unsigned* __restrict__ sflag)
{
  {
    int gidx = blockIdx.x * 256 + threadIdx.x;
    if (gidx < Hq) w1g[gidx] = vvec[gidx] * wcvec[gidx];
    if (gidx < Bq) { cnt[gidx] = 0u; sflag[gidx] = 0u; }
    if (gidx == 0) lacc[0] = 0.f;
  }

  __shared__ unsigned short As[2][64][36];
  __shared__ unsigned short Bs[2][64][36];

  int bid = blockIdx.x;
  const float* A; const float* W; bool isEf;
  int bm, bn;
  if (bid < 384) {
    A = enc; W = Wh; isEf = true;
    bm = bid % 32; bn = bid / 32;               // XCD affinity via bm%8
  } else {
    bid -= 384;
    A = dec; W = Wd; isEf = false;
    bm = bid % 8; bn = bid / 8;
  }
  const int m0 = bm * 64, n0 = bn * 64;

  const int ti = threadIdx.x;
  const int srow = ti >> 2, scol = (ti & 3) * 8;
  const float* pa = A + (size_t)(m0 + srow) * Hq + scol;
  const float* pw = W + (size_t)(n0 + srow) * Hq + scol;

  {
    f32x4 a0 = *(const f32x4*)pa, a1 = *(const f32x4*)(pa + 4);
    f32x4 w0 = *(const f32x4*)pw, w1 = *(const f32x4*)(pw + 4);
    bf16x8 av = cvt8(a0, a1), wv = cvt8(w0, w1);
    *(uint2*)&As[0][srow][scol]     = *(uint2*)&av;
    *(uint2*)&As[0][srow][scol + 4] = *((uint2*)&av + 1);
    *(uint2*)&Bs[0][srow][scol]     = *(uint2*)&wv;
    *(uint2*)&Bs[0][srow][scol + 4] = *((uint2*)&wv + 1);
  }
  __syncthreads();

  const int w = ti >> 6, ln = ti & 63;
  const int mh = (w >> 1) * 32, nh = (w & 1) * 32;
  const int rsel = ln & 15, kof = (ln >> 4) * 8;

  f32x4 acc[2][2] = {};
  for (int k = 0; k < 24; k++) {
    f32x4 na0, na1, nw0, nw1;
    if (k < 23) {
      const float* qa = pa + (k + 1) * 32;
      const float* qw = pw + (k + 1) * 32;
      na0 = *(const f32x4*)qa; na1 = *(const f32x4*)(qa + 4);
      nw0 = *(const f32x4*)qw; nw1 = *(const f32x4*)(qw + 4);
    }
    const int cur = k & 1;
    bf16x8 af[2], bfb[2];
#pragma unroll
    for (int tm = 0; tm < 2; tm++) {
      uint2 l0 = *(const uint2*)&As[cur][mh + tm * 16 + rsel][kof];
      uint2 l1 = *(const uint2*)&As[cur][mh + tm * 16 + rsel][kof + 4];
      bf16x8 f; *(uint2*)&f = l0; *((uint2*)&f + 1) = l1;
      af[tm] = f;
    }
#pragma unroll
    for (int tn = 0; tn < 2; tn++) {
      uint2 l0 = *(const uint2*)&Bs[cur][nh + tn * 16 + rsel][kof];
      uint2 l1 = *(const uint2*)&Bs[cur][nh + tn * 16 + rsel][kof + 4];
      bf16x8 f; *(uint2*)&f = l0; *((uint2*)&f + 1) = l1;
      bfb[tn] = f;
    }
#pragma unroll
    for (int tm = 0; tm < 2; tm++)
#pragma unroll
      for (int tn = 0; tn < 2; tn++)
        acc[tm][tn] = __builtin_amdgcn_mfma_f32_16x16x32_bf16(af[tm], bfb[tn], acc[tm][tn], 0, 0, 0);
    if (k < 23) {
      bf16x8 av = cvt8(na0, na1), wv = cvt8(nw0, nw1);
      const int nxt = cur ^ 1;
      *(uint2*)&As[nxt][srow][scol]     = *(uint2*)&av;
      *(uint2*)&As[nxt][srow][scol + 4] = *((uint2*)&av + 1);
      *(uint2*)&Bs[nxt][srow][scol]     = *(uint2*)&wv;
      *(uint2*)&Bs[nxt][srow][scol + 4] = *((uint2*)&wv + 1);
      __syncthreads();
    }
  }

  const int col = ln & 15, rb = (ln >> 4) * 4;
#pragma unroll
  for (int tm = 0; tm < 2; tm++)
#pragma unroll
    for (int tn = 0; tn < 2; tn++)
#pragma unroll
      for (int j = 0; j < 4; j++) {
        int r = m0 + mh + tm * 16 + rb + j, c = n0 + nh + tn * 16 + col;
        float val = acc[tm][tn][j];
        if (isEf) {
          efh[(size_t)r * Hq + c] =
              (__bf16)__builtin_amdgcn_exp2f(val * TANH_SCALE);
        } else {
          decfh[(size_t)r * Hq + c] =
              (__bf16)__builtin_amdgcn_exp2f((val + bd[c]) * TANH_SCALE);
        }
      }
}

// ---------------- fused tail: AB precompute + scan + ht -----------------------
// 712 blocks, all co-resident by construction (launch_bounds(256,3) -> >=3
// blocks/CU = 768 >= 712; LDS 38.4KB -> 4/CU), so spin-waits are safe
// regardless of dispatch order.
//   bid 0..511   : AB tiles (2 per block, shared dec stage) -> cnt[b] += 1 (of 64)
//   bid 512..519 : per-batch scan (spin cnt[b]==64) -> sflag[b] = 1
//   bid 520..711 : ht tiles (spin sflag[b]); block 520 finalizes loss
__global__ __launch_bounds__(256, 3) void tail_kernel(
    const __bf16* __restrict__ efh, const __bf16* __restrict__ decfh,
    const float* __restrict__ vvec, const float* __restrict__ w1g,
    const float* __restrict__ emask, const float* __restrict__ cov0,
    const float* __restrict__ dmask, const float* __restrict__ enc,
    float2* __restrict__ ab,
    float* __restrict__ out_attn, float* __restrict__ out_covf,
    float* __restrict__ out_ht, float* __restrict__ out_loss,
    float* __restrict__ lacc,
    unsigned* __restrict__ cnt, unsigned* __restrict__ sflag)
{
  __shared__ double smem_raw[4808];           // 38464 B, shared across paths
  const int bid = blockIdx.x;
  const int tid = threadIdx.x;

  if (bid < 512) {
    // ---------------- AB path ----------------
    unsigned short (*efs)[780] = (unsigned short(*)[780])smem_raw;                     // 24960 B
    unsigned short (*dts)[776] = (unsigned short(*)[776])((char*)smem_raw + 24960);    // 12416 B
    float (*part)[2]           = (float(*)[2])((char*)smem_raw + 37376);               // 1024 B
    const int b = bid & 7;
    const int rr = bid >> 3;                  // 0..63
    const int tt0 = (rr & 7) * TT;
    const int stb = (rr >> 3) * ST;           // 0..112

    for (int i = tid; i < TT * 192; i += 256) {
      int row = i / 192, c = (i % 192) * 4;
      *(uint2*)&dts[row][c] =
          *(const uint2*)(decfh + (size_t)(b * Tq + tt0 + row) * Hq + c);
    }

    const int hh = tid >> 7;
    const int pid = tid & 127;
    const int tl = pid >> 4, sl = pid & 15;
    const int hbase = hh * 384;
    const int hbu = __builtin_amdgcn_readfirstlane(hbase);
    const float* vp  = vvec + hbu;
    const float* w1p = w1g + hbu;

#pragma unroll
    for (int tile = 0; tile < 2; tile++) {
      const int st0 = stb + tile * 128;
      if (tile) __syncthreads();              // prior compute done before restage
      for (int i = tid; i < ST * 192; i += 256) {
        int row = i / 192, c = (i % 192) * 4;
        *(uint2*)&efs[row][c] =
            *(const uint2*)(efh + (size_t)(b * Sq + st0 + row) * Hq + c);
      }
      __syncthreads();

      float A = 0.f, B = 0.f;
#define BLO(x) __uint_as_float((x) << 16)
#define BHI(x) __uint_as_float((x) & 0xFFFF0000u)
#pragma unroll 4
      for (int j = 0; j < 384; j += 4) {
        uint2 eu = *(const uint2*)&efs[sl][hbase + j];
        uint2 du = *(const uint2*)&dts[tl][hbase + j];
        f32x4 v4 = *(const f32x4*)(vp + j);
        f32x4 w1 = *(const f32x4*)(w1p + j);
        float e2[4];
        e2[0] = BLO(eu.x) * BLO(du.x);
        e2[1] = BHI(eu.x) * BHI(du.x);
        e2[2] = BLO(eu.y) * BLO(du.y);
        e2[3] = BHI(eu.y) * BHI(du.y);
#pragma unroll
        for (int e = 0; e < 4; e++) {
          float rr2 = __builtin_amdgcn_rcpf(1.f + e2[e]);
          float t0 = 1.f - 2.f * rr2;
          float f1 = 1.f - t0 * t0;
          A += v4[e] * t0;
          B += w1[e] * f1;
        }
      }
#undef BLO
#undef BHI
      if (hh == 1) { part[pid][0] = A; part[pid][1] = B; }
      __syncthreads();
      if (hh == 0) {
        float2 outv;
        outv.x = A + part[pid][0];
        outv.y = B + part[pid][1];
        ab[(size_t)(b * Tq + tt0 + tl) * Sq + st0 + sl] = outv;
      }
    }
    __syncthreads();
    if (tid == 0) {
      __threadfence();
      __hip_atomic_fetch_add(&cnt[b], 1u, __ATOMIC_RELEASE, __HIP_MEMORY_SCOPE_AGENT);
    }
  } else if (bid < 520) {
    // ---------------- scan path ----------------
    float* zp   = (float*)smem_raw;           // [2][4]
    float* dms  = (float*)smem_raw + 8;       // [64]
    float* lred = (float*)smem_raw + 72;      // [4]
    const int b = bid - 512;
    if (tid == 0)
      while (__hip_atomic_load(&cnt[b], __ATOMIC_ACQUIRE, __HIP_MEMORY_SCOPE_AGENT) < 64u) {}
    if (tid < Tq) dms[tid] = dmask[b * Tq + tid];
    __syncthreads();                          // releases all threads when ready

    const int s = tid;
    const int w = s >> 6, ln = s & 63;
    const float em = emask[b * Sq + s];
    float cov = cov0[b * Sq + s];
    float lp = 0.f;
    const float2* P = ab + (size_t)b * Tq * Sq + s;
    float2 cur = P[0];

    for (int t = 0; t < Tq; t++) {
      float2 nxt = (t + 1 < Tq) ? P[(size_t)(t + 1) * Sq] : cur;
      float sc = cur.x + cov * cur.y;
      float E = __builtin_amdgcn_exp2f(sc * LOG2E) * em;
      float wsum = wave64_sum(E);
      if (ln == 0) zp[(t & 1) * 4 + w] = wsum;
      __syncthreads();
      float Z = zp[(t & 1) * 4 + 0] + zp[(t & 1) * 4 + 1] +
                zp[(t & 1) * 4 + 2] + zp[(t & 1) * 4 + 3];
      float at = E * __builtin_amdgcn_rcpf(Z);
      lp += fminf(at, cov) * dms[t];
      cov += at;
      out_attn[(size_t)(b * Tq + t) * Sq + s] = at;
      cur = nxt;
    }

    out_covf[b * Sq + s] = cov;
    float wl = wave64_sum(lp);
    if (ln == 0) lred[w] = wl;
    __syncthreads();
    if (tid == 0) {
      atomicAdd(lacc, lred[0] + lred[1] + lred[2] + lred[3]);
      __threadfence();
      __hip_atomic_store(&sflag[b], 1u, __ATOMIC_RELEASE, __HIP_MEMORY_SCOPE_AGENT);
    }
  } else {
    // ---------------- ht path ----------------
    float (*lat)[8] = (float(*)[8])smem_raw;  // [256][8] = 8192 B
    float* r4 = (float*)smem_raw + 2048;
    const int hidx = bid - 520;               // 0..191
    const int b = hidx / 24, r2 = hidx % 24, tc = r2 / 3, hc = r2 % 3;
    if (tid == 0)
      while (__hip_atomic_load(&sflag[b], __ATOMIC_ACQUIRE, __HIP_MEMORY_SCOPE_AGENT) == 0u) {}
    __syncthreads();

    const int h = hc * 256 + tid;
#pragma unroll
    for (int tt = 0; tt < 8; tt++)
      lat[tid][tt] = out_attn[(size_t)(b * Tq + tc * 8 + tt) * Sq + tid];
    __syncthreads();

    float acc[8] = {};
    const float* ep = enc + (size_t)(b * Sq) * Hq + h;
    for (int sb = 0; sb < Sq; sb += 8) {
      float e[8];
#pragma unroll
      for (int u = 0; u < 8; u++) e[u] = ep[(size_t)(sb + u) * Hq];
#pragma unroll
      for (int u = 0; u < 8; u++) {
        f32x4 a0 = *(const f32x4*)&lat[sb + u][0];
        f32x4 a1 = *(const f32x4*)&lat[sb + u][4];
        acc[0] += a0[0] * e[u]; acc[1] += a0[1] * e[u];
        acc[2] += a0[2] * e[u]; acc[3] += a0[3] * e[u];
        acc[4] += a1[0] * e[u]; acc[5] += a1[1] * e[u];
        acc[6] += a1[2] * e[u]; acc[7] += a1[3] * e[u];
      }
    }
#pragma unroll
    for (int tt = 0; tt < 8; tt++)
      out_ht[(size_t)(b * Tq + tc * 8 + tt) * Hq + h] = acc[tt];

    if (hidx == 0) {
      if (tid == 0)
        for (int bb = 0; bb < Bq; bb++)
          while (__hip_atomic_load(&sflag[bb], __ATOMIC_ACQUIRE, __HIP_MEMORY_SCOPE_AGENT) == 0u) {}
      __syncthreads();
      float s = 0.f;
      for (int i = tid; i < Bq * Tq; i += 256) s += dmask[i];
#pragma unroll
      for (int off = 32; off; off >>= 1) s += __shfl_xor(s, off);
      int w = tid >> 6, ln = tid & 63;
      if (ln == 0) r4[w] = s;
      __syncthreads();
      if (tid == 0) out_loss[0] = lacc[0] / (r4[0] + r4[1] + r4[2] + r4[3]);
    }
  }
}

extern "C" void kernel_launch(void* const* d_in, const int* in_sizes, int n_in,
                              void* d_out, int out_size, void* d_ws, size_t ws_size,
                              hipStream_t stream) {
  const float* dec   = (const float*)d_in[0];   // [8,64,768]
  const float* dmask = (const float*)d_in[1];   // [8,64]
  const float* enc   = (const float*)d_in[2];   // [8,256,768]
  const float* emask = (const float*)d_in[3];   // [8,256]
  const float* cov0  = (const float*)d_in[4];   // [8,256]
  const float* Wh    = (const float*)d_in[5];   // [768,768]
  const float* Wd    = (const float*)d_in[6];   // [768,768]
  const float* bd    = (const float*)d_in[7];   // [768]
  const float* wc    = (const float*)d_in[8];   // [768]
  const float* vv    = (const float*)d_in[9];   // [768]
  float* out = (float*)d_out;

  char* ws = (char*)d_ws;
  __bf16*   efh   = (__bf16*)ws;                 // 3145728 B
  __bf16*   decfh = (__bf16*)(ws + 3145728);     // 786432 B
  float2*   ab    = (float2*)(ws + 3932160);     // 1048576 B
  float*    w1g   = (float*)(ws + 4980736);      // 3072 B
  float*    lacc  = (float*)(ws + 4983808);      // 4 B
  unsigned* cnt   = (unsigned*)(ws + 4983872);   // 32 B (64B-aligned)
  unsigned* sflag = (unsigned*)(ws + 4983936);   // 32 B

  const size_t OFF_ATTN = (size_t)Bq * Tq * Hq;             // 393216
  const size_t OFF_LOSS = OFF_ATTN + (size_t)Bq * Tq * Sq;  // 524288
  const size_t OFF_COV  = OFF_LOSS + 1;                     // 524289

  proj_kernel<<<480, 256, 0, stream>>>(enc, dec, Wh, Wd, bd, wc, vv,
                                       efh, decfh, w1g, lacc, cnt, sflag);
  tail_kernel<<<712, 256, 0, stream>>>(efh, decfh, vv, w1g, emask, cov0,
                                       dmask, enc, ab,
                                       out + OFF_ATTN, out + OFF_COV,
                                       out, out + OFF_LOSS, lacc, cnt, sflag);
}

// Round 20
// 113.023 us; speedup vs baseline: 1.9279x; 1.9279x over previous
//
#include <hip/hip_runtime.h>

#define Bq 8
#define Tq 64
#define Sq 256
#define Hq 768
#define TT 8
#define ST 16

typedef float f32x4 __attribute__((ext_vector_type(4)));
typedef __bf16 bf16x8 __attribute__((ext_vector_type(8)));

#define TANH_SCALE 2.885390081777927f   // 2*log2(e): exp2(u*TS) = e^{2u}
#define LOG2E 1.4426950408889634f

// ---- DPP wave reduction -----------------------------------------------------
template <int Ctrl, int Rmask>
__device__ __forceinline__ float dpp_add_f(float v) {
  int t = __builtin_amdgcn_update_dpp(0, __float_as_int(v), Ctrl, Rmask, 0xF, true);
  return v + __int_as_float(t);
}
__device__ __forceinline__ float wave64_sum(float v) {
  v = dpp_add_f<0xB1, 0xF>(v);
  v = dpp_add_f<0x4E, 0xF>(v);
  v = dpp_add_f<0x141, 0xF>(v);
  v = dpp_add_f<0x140, 0xF>(v);
  v = dpp_add_f<0x142, 0xA>(v);
  v = dpp_add_f<0x143, 0xC>(v);
  return __int_as_float(__builtin_amdgcn_readlane(__float_as_int(v), 63));
}

__device__ __forceinline__ bf16x8 cvt8(f32x4 lo, f32x4 hi) {
  bf16x8 t;
  t[0] = (__bf16)lo[0]; t[1] = (__bf16)lo[1]; t[2] = (__bf16)lo[2]; t[3] = (__bf16)lo[3];
  t[4] = (__bf16)hi[0]; t[5] = (__bf16)hi[1]; t[6] = (__bf16)hi[2]; t[7] = (__bf16)hi[3];
  return t;
}

// ---------------- projection GEMMs (LDS-staged, double-buffered) --------------
// Stores PRE-EXPONENTIATED outputs E=exp2(TS*ef), D=exp2(TS*dec) as bf16.
// Side duty: w1 = v*wc stream, zero lacc + sync counters/flags (plain stores;
// end-of-kernel implicit release makes them visible to tail's atomics).
__global__ __launch_bounds__(256, 2) void proj_kernel(
    const float* __restrict__ enc, const float* __restrict__ dec,
    const float* __restrict__ Wh, const float* __restrict__ Wd,
    const float* __restrict__ bd,
    const float* __restrict__ wcvec, const float* __restrict__ vvec,
    __bf16* __restrict__ efh, __bf16* __restrict__ decfh,
    float* __restrict__ w1g, float* __restrict__ lacc,
    unsigned* __restrict__ cnt, unsigned* __restrict__ sflag)
{
  {
    int gidx = blockIdx.x * 256 + threadIdx.x;
    if (gidx < Hq) w1g[gidx] = vvec[gidx] * wcvec[gidx];
    if (gidx < Bq) { cnt[gidx] = 0u; sflag[gidx] = 0u; }
    if (gidx == 0) lacc[0] = 0.f;
  }

  __shared__ unsigned short As[2][64][36];
  __shared__ unsigned short Bs[2][64][36];

  int bid = blockIdx.x;
  const float* A; const float* W; bool isEf;
  int bm, bn;
  if (bid < 384) {
    A = enc; W = Wh; isEf = true;
    bm = bid % 32; bn = bid / 32;               // XCD affinity via bm%8
  } else {
    bid -= 384;
    A = dec; W = Wd; isEf = false;
    bm = bid % 8; bn = bid / 8;
  }
  const int m0 = bm * 64, n0 = bn * 64;

  const int ti = threadIdx.x;
  const int srow = ti >> 2, scol = (ti & 3) * 8;
  const float* pa = A + (size_t)(m0 + srow) * Hq + scol;
  const float* pw = W + (size_t)(n0 + srow) * Hq + scol;

  {
    f32x4 a0 = *(const f32x4*)pa, a1 = *(const f32x4*)(pa + 4);
    f32x4 w0 = *(const f32x4*)pw, w1 = *(const f32x4*)(pw + 4);
    bf16x8 av = cvt8(a0, a1), wv = cvt8(w0, w1);
    *(uint2*)&As[0][srow][scol]     = *(uint2*)&av;
    *(uint2*)&As[0][srow][scol + 4] = *((uint2*)&av + 1);
    *(uint2*)&Bs[0][srow][scol]     = *(uint2*)&wv;
    *(uint2*)&Bs[0][srow][scol + 4] = *((uint2*)&wv + 1);
  }
  __syncthreads();

  const int w = ti >> 6, ln = ti & 63;
  const int mh = (w >> 1) * 32, nh = (w & 1) * 32;
  const int rsel = ln & 15, kof = (ln >> 4) * 8;

  f32x4 acc[2][2] = {};
  for (int k = 0; k < 24; k++) {
    f32x4 na0, na1, nw0, nw1;
    if (k < 23) {
      const float* qa = pa + (k + 1) * 32;
      const float* qw = pw + (k + 1) * 32;
      na0 = *(const f32x4*)qa; na1 = *(const f32x4*)(qa + 4);
      nw0 = *(const f32x4*)qw; nw1 = *(const f32x4*)(qw + 4);
    }
    const int cur = k & 1;
    bf16x8 af[2], bfb[2];
#pragma unroll
    for (int tm = 0; tm < 2; tm++) {
      uint2 l0 = *(const uint2*)&As[cur][mh + tm * 16 + rsel][kof];
      uint2 l1 = *(const uint2*)&As[cur][mh + tm * 16 + rsel][kof + 4];
      bf16x8 f; *(uint2*)&f = l0; *((uint2*)&f + 1) = l1;
      af[tm] = f;
    }
#pragma unroll
    for (int tn = 0; tn < 2; tn++) {
      uint2 l0 = *(const uint2*)&Bs[cur][nh + tn * 16 + rsel][kof];
      uint2 l1 = *(const uint2*)&Bs[cur][nh + tn * 16 + rsel][kof + 4];
      bf16x8 f; *(uint2*)&f = l0; *((uint2*)&f + 1) = l1;
      bfb[tn] = f;
    }
#pragma unroll
    for (int tm = 0; tm < 2; tm++)
#pragma unroll
      for (int tn = 0; tn < 2; tn++)
        acc[tm][tn] = __builtin_amdgcn_mfma_f32_16x16x32_bf16(af[tm], bfb[tn], acc[tm][tn], 0, 0, 0);
    if (k < 23) {
      bf16x8 av = cvt8(na0, na1), wv = cvt8(nw0, nw1);
      const int nxt = cur ^ 1;
      *(uint2*)&As[nxt][srow][scol]     = *(uint2*)&av;
      *(uint2*)&As[nxt][srow][scol + 4] = *((uint2*)&av + 1);
      *(uint2*)&Bs[nxt][srow][scol]     = *(uint2*)&wv;
      *(uint2*)&Bs[nxt][srow][scol + 4] = *((uint2*)&wv + 1);
      __syncthreads();
    }
  }

  const int col = ln & 15, rb = (ln >> 4) * 4;
#pragma unroll
  for (int tm = 0; tm < 2; tm++)
#pragma unroll
    for (int tn = 0; tn < 2; tn++)
#pragma unroll
      for (int j = 0; j < 4; j++) {
        int r = m0 + mh + tm * 16 + rb + j, c = n0 + nh + tn * 16 + col;
        float val = acc[tm][tn][j];
        if (isEf) {
          efh[(size_t)r * Hq + c] =
              (__bf16)__builtin_amdgcn_exp2f(val * TANH_SCALE);
        } else {
          decfh[(size_t)r * Hq + c] =
              (__bf16)__builtin_amdgcn_exp2f((val + bd[c]) * TANH_SCALE);
        }
      }
}

// ---------------- fused tail: AB + scan + ht ----------------------------------
// 712 blocks, all co-resident (launch_bounds(256,3): 3 blocks/CU * 256 = 768
// >= 712; LDS 38.4KB -> 4/CU). ALL handoffs use RELAXED agent atomics through
// the IC (no fences, no acquire spins -> no cache-invalidation thrash; the
// r19 regression). __syncthreads() drains each wave's stores (vmcnt(0) before
// barrier) so a post-barrier counter add orders correctly at the IC.
__global__ __launch_bounds__(256, 3) void tail_kernel(
    const __bf16* __restrict__ efh, const __bf16* __restrict__ decfh,
    const float* __restrict__ vvec, const float* __restrict__ w1g,
    const float* __restrict__ emask, const float* __restrict__ cov0,
    const float* __restrict__ dmask, const float* __restrict__ enc,
    float2* __restrict__ ab,
    float* __restrict__ out_attn, float* __restrict__ out_covf,
    float* __restrict__ out_ht, float* __restrict__ out_loss,
    float* __restrict__ lacc,
    unsigned* __restrict__ cnt, unsigned* __restrict__ sflag)
{
  __shared__ double smem_raw[4808];           // 38464 B, shared across paths
  const int bid = blockIdx.x;
  const int tid = threadIdx.x;

  if (bid < 512) {
    // ---------------- AB path: 2 tiles/block, shared dec stage ----------------
    unsigned short (*efs)[780] = (unsigned short(*)[780])smem_raw;                  // 24960 B
    unsigned short (*dts)[776] = (unsigned short(*)[776])((char*)smem_raw + 24960); // 12416 B
    float (*part)[2]           = (float(*)[2])((char*)smem_raw + 37376);            // 1024 B
    const int b = bid & 7;                    // XCD-affine with producers
    const int rr = bid >> 3;                  // 0..63
    const int tt0 = (rr & 7) * TT;
    const int stb = (rr >> 3) * ST;           // 0..112

    for (int i = tid; i < TT * 192; i += 256) {
      int row = i / 192, c = (i % 192) * 4;
      *(uint2*)&dts[row][c] =
          *(const uint2*)(decfh + (size_t)(b * Tq + tt0 + row) * Hq + c);
    }

    const int hh = tid >> 7;
    const int pid = tid & 127;
    const int tl = pid >> 4, sl = pid & 15;
    const int hbase = hh * 384;
    const int hbu = __builtin_amdgcn_readfirstlane(hbase);
    const float* vp  = vvec + hbu;
    const float* w1p = w1g + hbu;

#pragma unroll
    for (int tile = 0; tile < 2; tile++) {
      const int st0 = stb + tile * 128;
      if (tile) __syncthreads();
      for (int i = tid; i < ST * 192; i += 256) {
        int row = i / 192, c = (i % 192) * 4;
        *(uint2*)&efs[row][c] =
            *(const uint2*)(efh + (size_t)(b * Sq + st0 + row) * Hq + c);
      }
      __syncthreads();

      float A = 0.f, B = 0.f;
#define BLO(x) __uint_as_float((x) << 16)
#define BHI(x) __uint_as_float((x) & 0xFFFF0000u)
#pragma unroll 4
      for (int j = 0; j < 384; j += 4) {
        uint2 eu = *(const uint2*)&efs[sl][hbase + j];
        uint2 du = *(const uint2*)&dts[tl][hbase + j];
        f32x4 v4 = *(const f32x4*)(vp + j);
        f32x4 w1 = *(const f32x4*)(w1p + j);
        float e2[4];
        e2[0] = BLO(eu.x) * BLO(du.x);
        e2[1] = BHI(eu.x) * BHI(du.x);
        e2[2] = BLO(eu.y) * BLO(du.y);
        e2[3] = BHI(eu.y) * BHI(du.y);
#pragma unroll
        for (int e = 0; e < 4; e++) {
          float rr2 = __builtin_amdgcn_rcpf(1.f + e2[e]);
          float t0 = 1.f - 2.f * rr2;
          float f1 = 1.f - t0 * t0;
          A += v4[e] * t0;
          B += w1[e] * f1;
        }
      }
#undef BLO
#undef BHI
      if (hh == 1) { part[pid][0] = A; part[pid][1] = B; }
      __syncthreads();
      if (hh == 0) {
        union { float2 f; unsigned long long u; } cv;
        cv.f.x = A + part[pid][0];
        cv.f.y = B + part[pid][1];
        // IC write-through (bypasses L2; no stale-line or writeback hazard)
        __hip_atomic_store(
            (unsigned long long*)&ab[(size_t)(b * Tq + tt0 + tl) * Sq + st0 + sl],
            cv.u, __ATOMIC_RELAXED, __HIP_MEMORY_SCOPE_AGENT);
      }
    }
    __syncthreads();    // drains every wave's ab stores (vmcnt(0) pre-barrier)
    if (tid == 0)
      __hip_atomic_fetch_add(&cnt[b], 1u, __ATOMIC_RELAXED, __HIP_MEMORY_SCOPE_AGENT);
  } else if (bid < 520) {
    // ---------------- scan path (1 block per batch) ---------------------------
    float* zp   = (float*)smem_raw;           // [2][4]
    float* dms  = (float*)smem_raw + 8;       // [64]
    float* lred = (float*)smem_raw + 72;      // [4]
    const int b = bid - 512;
    if (tid == 0)
      while (__hip_atomic_load(&cnt[b], __ATOMIC_RELAXED, __HIP_MEMORY_SCOPE_AGENT) < 64u)
        __builtin_amdgcn_s_sleep(2);
    if (tid < Tq) dms[tid] = dmask[b * Tq + tid];
    __syncthreads();

    const int s = tid;
    const int w = s >> 6, ln = s & 63;
    const float em = emask[b * Sq + s];
    float cov = cov0[b * Sq + s];
    float lp = 0.f;
    const unsigned long long* P =
        (const unsigned long long*)(ab + (size_t)b * Tq * Sq + s);
    union { unsigned long long u; float2 f; } cur, nxt;
    cur.u = __hip_atomic_load(P, __ATOMIC_RELAXED, __HIP_MEMORY_SCOPE_AGENT);

    for (int t = 0; t < Tq; t++) {
      if (t + 1 < Tq)
        nxt.u = __hip_atomic_load(P + (size_t)(t + 1) * Sq,
                                  __ATOMIC_RELAXED, __HIP_MEMORY_SCOPE_AGENT);
      else nxt = cur;
      float sc = cur.f.x + cov * cur.f.y;
      float E = __builtin_amdgcn_exp2f(sc * LOG2E) * em;
      float wsum = wave64_sum(E);
      if (ln == 0) zp[(t & 1) * 4 + w] = wsum;
      __syncthreads();
      float Z = zp[(t & 1) * 4 + 0] + zp[(t & 1) * 4 + 1] +
                zp[(t & 1) * 4 + 2] + zp[(t & 1) * 4 + 3];
      float at = E * __builtin_amdgcn_rcpf(Z);
      lp += fminf(at, cov) * dms[t];
      cov += at;
      __hip_atomic_store(&out_attn[(size_t)(b * Tq + t) * Sq + s], at,
                         __ATOMIC_RELAXED, __HIP_MEMORY_SCOPE_AGENT);
      cur = nxt;
    }

    out_covf[b * Sq + s] = cov;               // host-only consumer
    float wl = wave64_sum(lp);
    if (ln == 0) lred[w] = wl;
    __syncthreads();                          // drains attn stores of all waves
    if (tid == 0) {
      atomicAdd(lacc, lred[0] + lred[1] + lred[2] + lred[3]);
      asm volatile("s_waitcnt vmcnt(0)" ::: "memory");  // lacc add at IC first
      __hip_atomic_store(&sflag[b], 1u, __ATOMIC_RELAXED, __HIP_MEMORY_SCOPE_AGENT);
    }
  } else {
    // ---------------- ht path -------------------------------------------------
    float (*lat)[8] = (float(*)[8])smem_raw;  // [256][8] = 8192 B
    float* r4 = (float*)smem_raw + 2048;
    const int hidx = bid - 520;               // 0..191
    const int b = hidx / 24, r2 = hidx % 24, tc = r2 / 3, hc = r2 % 3;
    if (tid == 0)
      while (__hip_atomic_load(&sflag[b], __ATOMIC_RELAXED, __HIP_MEMORY_SCOPE_AGENT) == 0u)
        __builtin_amdgcn_s_sleep(2);
    __syncthreads();

    const int h = hc * 256 + tid;
#pragma unroll
    for (int tt = 0; tt < 8; tt++)
      lat[tid][tt] = __hip_atomic_load(
          &out_attn[(size_t)(b * Tq + tc * 8 + tt) * Sq + tid],
          __ATOMIC_RELAXED, __HIP_MEMORY_SCOPE_AGENT);
    __syncthreads();

    float acc[8] = {};
    const float* ep = enc + (size_t)(b * Sq) * Hq + h;
    for (int sb = 0; sb < Sq; sb += 8) {
      float e[8];
#pragma unroll
      for (int u = 0; u < 8; u++) e[u] = ep[(size_t)(sb + u) * Hq];
#pragma unroll
      for (int u = 0; u < 8; u++) {
        f32x4 a0 = *(const f32x4*)&lat[sb + u][0];
        f32x4 a1 = *(const f32x4*)&lat[sb + u][4];
        acc[0] += a0[0] * e[u]; acc[1] += a0[1] * e[u];
        acc[2] += a0[2] * e[u]; acc[3] += a0[3] * e[u];
        acc[4] += a1[0] * e[u]; acc[5] += a1[1] * e[u];
        acc[6] += a1[2] * e[u]; acc[7] += a1[3] * e[u];
      }
    }
#pragma unroll
    for (int tt = 0; tt < 8; tt++)
      out_ht[(size_t)(b * Tq + tc * 8 + tt) * Hq + h] = acc[tt];

    if (hidx == 0) {
      if (tid == 0)
        for (int bb = 0; bb < Bq; bb++)
          while (__hip_atomic_load(&sflag[bb], __ATOMIC_RELAXED, __HIP_MEMORY_SCOPE_AGENT) == 0u)
            __builtin_amdgcn_s_sleep(2);
      __syncthreads();
      float s = 0.f;
      for (int i = tid; i < Bq * Tq; i += 256) s += dmask[i];
#pragma unroll
      for (int off = 32; off; off >>= 1) s += __shfl_xor(s, off);
      int w = tid >> 6, ln = tid & 63;
      if (ln == 0) r4[w] = s;
      __syncthreads();
      if (tid == 0)
        out_loss[0] = __hip_atomic_load(lacc, __ATOMIC_RELAXED, __HIP_MEMORY_SCOPE_AGENT)
                      / (r4[0] + r4[1] + r4[2] + r4[3]);
    }
  }
}

extern "C" void kernel_launch(void* const* d_in, const int* in_sizes, int n_in,
                              void* d_out, int out_size, void* d_ws, size_t ws_size,
                              hipStream_t stream) {
  const float* dec   = (const float*)d_in[0];   // [8,64,768]
  const float* dmask = (const float*)d_in[1];   // [8,64]
  const float* enc   = (const float*)d_in[2];   // [8,256,768]
  const float* emask = (const float*)d_in[3];   // [8,256]
  const float* cov0  = (const float*)d_in[4];   // [8,256]
  const float* Wh    = (const float*)d_in[5];   // [768,768]
  const float* Wd    = (const float*)d_in[6];   // [768,768]
  const float* bd    = (const float*)d_in[7];   // [768]
  const float* wc    = (const float*)d_in[8];   // [768]
  const float* vv    = (const float*)d_in[9];   // [768]
  float* out = (float*)d_out;

  char* ws = (char*)d_ws;
  __bf16*   efh   = (__bf16*)ws;                 // 3145728 B
  __bf16*   decfh = (__bf16*)(ws + 3145728);     // 786432 B
  float2*   ab    = (float2*)(ws + 3932160);     // 1048576 B
  float*    w1g   = (float*)(ws + 4980736);      // 3072 B
  float*    lacc  = (float*)(ws + 4983808);      // 4 B
  unsigned* cnt   = (unsigned*)(ws + 4983872);   // 32 B (64B-aligned)
  unsigned* sflag = (unsigned*)(ws + 4983936);   // 32 B

  const size_t OFF_ATTN = (size_t)Bq * Tq * Hq;             // 393216
  const size_t OFF_LOSS = OFF_ATTN + (size_t)Bq * Tq * Sq;  // 524288
  const size_t OFF_COV  = OFF_LOSS + 1;                     // 524289

  proj_kernel<<<480, 256, 0, stream>>>(enc, dec, Wh, Wd, bd, wc, vv,
                                       efh, decfh, w1g, lacc, cnt, sflag);
  tail_kernel<<<712, 256, 0, stream>>>(efh, decfh, vv, w1g, emask, cov0,
                                       dmask, enc, ab,
                                       out + OFF_ATTN, out + OFF_COV,
                                       out, out + OFF_LOSS, lacc, cnt, sflag);
}

// Round 22
// 107.312 us; speedup vs baseline: 2.0305x; 1.0532x over previous
//
#include <hip/hip_runtime.h>

#define Bq 8
#define Tq 64
#define Sq 256
#define Hq 768
#define TT 8
#define ST 16

typedef float f32x4 __attribute__((ext_vector_type(4)));
typedef __bf16 bf16x8 __attribute__((ext_vector_type(8)));

#define TANH_SCALE 2.885390081777927f   // 2*log2(e): exp2(u*TS) = e^{2u}
#define LOG2E 1.4426950408889634f

// ---- DPP wave reduction -----------------------------------------------------
template <int Ctrl, int Rmask>
__device__ __forceinline__ float dpp_add_f(float v) {
  int t = __builtin_amdgcn_update_dpp(0, __float_as_int(v), Ctrl, Rmask, 0xF, true);
  return v + __int_as_float(t);
}
__device__ __forceinline__ float wave64_sum(float v) {
  v = dpp_add_f<0xB1, 0xF>(v);
  v = dpp_add_f<0x4E, 0xF>(v);
  v = dpp_add_f<0x141, 0xF>(v);
  v = dpp_add_f<0x140, 0xF>(v);
  v = dpp_add_f<0x142, 0xA>(v);
  v = dpp_add_f<0x143, 0xC>(v);
  return __int_as_float(__builtin_amdgcn_readlane(__float_as_int(v), 63));
}

__device__ __forceinline__ bf16x8 cvt8(f32x4 lo, f32x4 hi) {
  bf16x8 t;
  t[0] = (__bf16)lo[0]; t[1] = (__bf16)lo[1]; t[2] = (__bf16)lo[2]; t[3] = (__bf16)lo[3];
  t[4] = (__bf16)hi[0]; t[5] = (__bf16)hi[1]; t[6] = (__bf16)hi[2]; t[7] = (__bf16)hi[3];
  return t;
}

// ---------------- projection GEMMs (LDS-staged, double-buffered) --------------
// Stores PRE-EXPONENTIATED outputs E=exp2(TS*ef), D=exp2(TS*dec) as bf16.
// Side duty: w1 = v*wc stream, zero lacc + sync counters/flags.
__global__ __launch_bounds__(256, 2) void proj_kernel(
    const float* __restrict__ enc, const float* __restrict__ dec,
    const float* __restrict__ Wh, const float* __restrict__ Wd,
    const float* __restrict__ bd,
    const float* __restrict__ wcvec, const float* __restrict__ vvec,
    __bf16* __restrict__ efh, __bf16* __restrict__ decfh,
    float* __restrict__ w1g, float* __restrict__ lacc,
    unsigned* __restrict__ cnt, unsigned* __restrict__ sflag)
{
  {
    int gidx = blockIdx.x * 256 + threadIdx.x;
    if (gidx < Hq) w1g[gidx] = vvec[gidx] * wcvec[gidx];
    if (gidx < Bq) { cnt[gidx] = 0u; sflag[gidx] = 0u; }
    if (gidx == 0) lacc[0] = 0.f;
  }

  __shared__ unsigned short As[2][64][36];
  __shared__ unsigned short Bs[2][64][36];

  int bid = blockIdx.x;
  const float* A; const float* W; bool isEf;
  int bm, bn;
  if (bid < 384) {
    A = enc; W = Wh; isEf = true;
    bm = bid % 32; bn = bid / 32;               // XCD affinity via bm%8
  } else {
    bid -= 384;
    A = dec; W = Wd; isEf = false;
    bm = bid % 8; bn = bid / 8;
  }
  const int m0 = bm * 64, n0 = bn * 64;

  const int ti = threadIdx.x;
  const int srow = ti >> 2, scol = (ti & 3) * 8;
  const float* pa = A + (size_t)(m0 + srow) * Hq + scol;
  const float* pw = W + (size_t)(n0 + srow) * Hq + scol;

  {
    f32x4 a0 = *(const f32x4*)pa, a1 = *(const f32x4*)(pa + 4);
    f32x4 w0 = *(const f32x4*)pw, w1 = *(const f32x4*)(pw + 4);
    bf16x8 av = cvt8(a0, a1), wv = cvt8(w0, w1);
    *(uint2*)&As[0][srow][scol]     = *(uint2*)&av;
    *(uint2*)&As[0][srow][scol + 4] = *((uint2*)&av + 1);
    *(uint2*)&Bs[0][srow][scol]     = *(uint2*)&wv;
    *(uint2*)&Bs[0][srow][scol + 4] = *((uint2*)&wv + 1);
  }
  __syncthreads();

  const int w = ti >> 6, ln = ti & 63;
  const int mh = (w >> 1) * 32, nh = (w & 1) * 32;
  const int rsel = ln & 15, kof = (ln >> 4) * 8;

  f32x4 acc[2][2] = {};
  for (int k = 0; k < 24; k++) {
    f32x4 na0, na1, nw0, nw1;
    if (k < 23) {
      const float* qa = pa + (k + 1) * 32;
      const float* qw = pw + (k + 1) * 32;
      na0 = *(const f32x4*)qa; na1 = *(const f32x4*)(qa + 4);
      nw0 = *(const f32x4*)qw; nw1 = *(const f32x4*)(qw + 4);
    }
    const int cur = k & 1;
    bf16x8 af[2], bfb[2];
#pragma unroll
    for (int tm = 0; tm < 2; tm++) {
      uint2 l0 = *(const uint2*)&As[cur][mh + tm * 16 + rsel][kof];
      uint2 l1 = *(const uint2*)&As[cur][mh + tm * 16 + rsel][kof + 4];
      bf16x8 f; *(uint2*)&f = l0; *((uint2*)&f + 1) = l1;
      af[tm] = f;
    }
#pragma unroll
    for (int tn = 0; tn < 2; tn++) {
      uint2 l0 = *(const uint2*)&Bs[cur][nh + tn * 16 + rsel][kof];
      uint2 l1 = *(const uint2*)&Bs[cur][nh + tn * 16 + rsel][kof + 4];
      bf16x8 f; *(uint2*)&f = l0; *((uint2*)&f + 1) = l1;
      bfb[tn] = f;
    }
#pragma unroll
    for (int tm = 0; tm < 2; tm++)
#pragma unroll
      for (int tn = 0; tn < 2; tn++)
        acc[tm][tn] = __builtin_amdgcn_mfma_f32_16x16x32_bf16(af[tm], bfb[tn], acc[tm][tn], 0, 0, 0);
    if (k < 23) {
      bf16x8 av = cvt8(na0, na1), wv = cvt8(nw0, nw1);
      const int nxt = cur ^ 1;
      *(uint2*)&As[nxt][srow][scol]     = *(uint2*)&av;
      *(uint2*)&As[nxt][srow][scol + 4] = *((uint2*)&av + 1);
      *(uint2*)&Bs[nxt][srow][scol]     = *(uint2*)&wv;
      *(uint2*)&Bs[nxt][srow][scol + 4] = *((uint2*)&wv + 1);
      __syncthreads();
    }
  }

  const int col = ln & 15, rb = (ln >> 4) * 4;
#pragma unroll
  for (int tm = 0; tm < 2; tm++)
#pragma unroll
    for (int tn = 0; tn < 2; tn++)
#pragma unroll
      for (int j = 0; j < 4; j++) {
        int r = m0 + mh + tm * 16 + rb + j, c = n0 + nh + tn * 16 + col;
        float val = acc[tm][tn][j];
        if (isEf) {
          efh[(size_t)r * Hq + c] =
              (__bf16)__builtin_amdgcn_exp2f(val * TANH_SCALE);
        } else {
          decfh[(size_t)r * Hq + c] =
              (__bf16)__builtin_amdgcn_exp2f((val + bd[c]) * TANH_SCALE);
        }
      }
}

// ---------------- fused tail: AB everywhere, then MORPH -----------------------
// 1024 blocks = exactly 4/CU co-resident (launch_bounds(256,4), LDS 38.4KB).
// Every block computes ONE AB tile at full occupancy; 128 producers per batch
// bump cnt[b] (scan waits for 128 — r21 bug was waiting for 64). Then blocks
// 0..7 morph into the per-batch scan, 8..199 into ht tiles, rest exit.
// All handoffs: RELAXED agent atomics via the IC (r20-proven; no fences).
__global__ __launch_bounds__(256, 4) void tail_kernel(
    const __bf16* __restrict__ efh, const __bf16* __restrict__ decfh,
    const float* __restrict__ vvec, const float* __restrict__ w1g,
    const float* __restrict__ emask, const float* __restrict__ cov0,
    const float* __restrict__ dmask, const float* __restrict__ enc,
    float2* __restrict__ ab,
    float* __restrict__ out_attn, float* __restrict__ out_covf,
    float* __restrict__ out_ht, float* __restrict__ out_loss,
    float* __restrict__ lacc,
    unsigned* __restrict__ cnt, unsigned* __restrict__ sflag)
{
  __shared__ double smem_raw[4808];           // 38464 B, reused across phases
  const int bid = blockIdx.x;
  const int tid = threadIdx.x;

  // ================= AB phase (all 1024 blocks) ================
  {
    unsigned short (*efs)[780] = (unsigned short(*)[780])smem_raw;                  // 24960 B
    unsigned short (*dts)[776] = (unsigned short(*)[776])((char*)smem_raw + 24960); // 12416 B
    float (*part)[2]           = (float(*)[2])((char*)smem_raw + 37376);            // 1024 B
    const int b = bid & 7;                    // XCD-affine
    const int rr = bid >> 3;                  // 0..127
    const int tt0 = (rr & 7) * TT;
    const int st0 = (rr >> 3) * ST;

    for (int i = tid; i < ST * 192; i += 256) {
      int row = i / 192, c = (i % 192) * 4;
      *(uint2*)&efs[row][c] =
          *(const uint2*)(efh + (size_t)(b * Sq + st0 + row) * Hq + c);
    }
    for (int i = tid; i < TT * 192; i += 256) {
      int row = i / 192, c = (i % 192) * 4;
      *(uint2*)&dts[row][c] =
          *(const uint2*)(decfh + (size_t)(b * Tq + tt0 + row) * Hq + c);
    }
    __syncthreads();

    const int hh = tid >> 7;
    const int pid = tid & 127;
    const int tl = pid >> 4, sl = pid & 15;
    const int hbase = hh * 384;
    const int hbu = __builtin_amdgcn_readfirstlane(hbase);
    const float* vp  = vvec + hbu;
    const float* w1p = w1g + hbu;

    float A = 0.f, B = 0.f;
#define BLO(x) __uint_as_float((x) << 16)
#define BHI(x) __uint_as_float((x) & 0xFFFF0000u)
#pragma unroll 4
    for (int j = 0; j < 384; j += 4) {
      uint2 eu = *(const uint2*)&efs[sl][hbase + j];
      uint2 du = *(const uint2*)&dts[tl][hbase + j];
      f32x4 v4 = *(const f32x4*)(vp + j);
      f32x4 w1 = *(const f32x4*)(w1p + j);
      float e2[4];
      e2[0] = BLO(eu.x) * BLO(du.x);
      e2[1] = BHI(eu.x) * BHI(du.x);
      e2[2] = BLO(eu.y) * BLO(du.y);
      e2[3] = BHI(eu.y) * BHI(du.y);
#pragma unroll
      for (int e = 0; e < 4; e++) {
        float rr2 = __builtin_amdgcn_rcpf(1.f + e2[e]);
        float t0 = 1.f - 2.f * rr2;
        float f1 = 1.f - t0 * t0;
        A += v4[e] * t0;
        B += w1[e] * f1;
      }
    }
#undef BLO
#undef BHI
    if (hh == 1) { part[pid][0] = A; part[pid][1] = B; }
    __syncthreads();
    if (hh == 0) {
      union { float2 f; unsigned long long u; } cv;
      cv.f.x = A + part[pid][0];
      cv.f.y = B + part[pid][1];
      __hip_atomic_store(
          (unsigned long long*)&ab[(size_t)(b * Tq + tt0 + tl) * Sq + st0 + sl],
          cv.u, __ATOMIC_RELAXED, __HIP_MEMORY_SCOPE_AGENT);
    }
    __syncthreads();   // drains all waves' ab stores (vmcnt(0) pre-barrier)
    if (tid == 0)
      __hip_atomic_fetch_add(&cnt[b], 1u, __ATOMIC_RELAXED, __HIP_MEMORY_SCOPE_AGENT);
  }

  if (bid >= 200) return;   // 824 blocks exit, freeing slots + L2

  // ================= morph: scan (bid 0..7) ================
  if (bid < 8) {
    float* zp   = (float*)smem_raw;           // [2][4]
    float* dms  = (float*)smem_raw + 8;       // [64]
    float* lred = (float*)smem_raw + 72;      // [4]
    const int b = bid;
    if (tid == 0)
      while (__hip_atomic_load(&cnt[b], __ATOMIC_RELAXED, __HIP_MEMORY_SCOPE_AGENT) < 128u)
        __builtin_amdgcn_s_sleep(2);
    if (tid < Tq) dms[tid] = dmask[b * Tq + tid];
    __syncthreads();

    const int s = tid;
    const int w = s >> 6, ln = s & 63;
    const float em = emask[b * Sq + s];
    float cov = cov0[b * Sq + s];
    float lp = 0.f;
    const unsigned long long* P =
        (const unsigned long long*)(ab + (size_t)b * Tq * Sq + s);
    union { unsigned long long u; float2 f; } cur, nxt;
    cur.u = __hip_atomic_load(P, __ATOMIC_RELAXED, __HIP_MEMORY_SCOPE_AGENT);

    for (int t = 0; t < Tq; t++) {
      if (t + 1 < Tq)
        nxt.u = __hip_atomic_load(P + (size_t)(t + 1) * Sq,
                                  __ATOMIC_RELAXED, __HIP_MEMORY_SCOPE_AGENT);
      else nxt = cur;
      float sc = cur.f.x + cov * cur.f.y;
      float E = __builtin_amdgcn_exp2f(sc * LOG2E) * em;
      float wsum = wave64_sum(E);
      if (ln == 0) zp[(t & 1) * 4 + w] = wsum;
      __syncthreads();
      float Z = zp[(t & 1) * 4 + 0] + zp[(t & 1) * 4 + 1] +
                zp[(t & 1) * 4 + 2] + zp[(t & 1) * 4 + 3];
      float at = E * __builtin_amdgcn_rcpf(Z);
      lp += fminf(at, cov) * dms[t];
      cov += at;
      __hip_atomic_store(&out_attn[(size_t)(b * Tq + t) * Sq + s], at,
                         __ATOMIC_RELAXED, __HIP_MEMORY_SCOPE_AGENT);
      cur = nxt;
    }

    out_covf[b * Sq + s] = cov;               // host-only consumer
    float wl = wave64_sum(lp);
    if (ln == 0) lred[w] = wl;
    __syncthreads();                          // drains attn stores of all waves
    if (tid == 0) {
      atomicAdd(lacc, lred[0] + lred[1] + lred[2] + lred[3]);
      asm volatile("s_waitcnt vmcnt(0)" ::: "memory");
      __hip_atomic_store(&sflag[b], 1u, __ATOMIC_RELAXED, __HIP_MEMORY_SCOPE_AGENT);
    }
    return;
  }

  // ================= morph: ht (bid 8..199) ================
  {
    float (*lat)[8] = (float(*)[8])smem_raw;  // [256][8] = 8192 B
    float* r4 = (float*)smem_raw + 2048;
    const int hidx = bid - 8;                 // 0..191
    const int b = hidx / 24, r2 = hidx % 24, tc = r2 / 3, hc = r2 % 3;
    if (tid == 0)
      while (__hip_atomic_load(&sflag[b], __ATOMIC_RELAXED, __HIP_MEMORY_SCOPE_AGENT) == 0u)
        __builtin_amdgcn_s_sleep(2);
    __syncthreads();

    const int h = hc * 256 + tid;
#pragma unroll
    for (int tt = 0; tt < 8; tt++)
      lat[tid][tt] = __hip_atomic_load(
          &out_attn[(size_t)(b * Tq + tc * 8 + tt) * Sq + tid],
          __ATOMIC_RELAXED, __HIP_MEMORY_SCOPE_AGENT);
    __syncthreads();

    float acc[8] = {};
    const float* ep = enc + (size_t)(b * Sq) * Hq + h;
    for (int sb = 0; sb < Sq; sb += 8) {
      float e[8];
#pragma unroll
      for (int u = 0; u < 8; u++) e[u] = ep[(size_t)(sb + u) * Hq];
#pragma unroll
      for (int u = 0; u < 8; u++) {
        f32x4 a0 = *(const f32x4*)&lat[sb + u][0];
        f32x4 a1 = *(const f32x4*)&lat[sb + u][4];
        acc[0] += a0[0] * e[u]; acc[1] += a0[1] * e[u];
        acc[2] += a0[2] * e[u]; acc[3] += a0[3] * e[u];
        acc[4] += a1[0] * e[u]; acc[5] += a1[1] * e[u];
        acc[6] += a1[2] * e[u]; acc[7] += a1[3] * e[u];
      }
    }
#pragma unroll
    for (int tt = 0; tt < 8; tt++)
      out_ht[(size_t)(b * Tq + tc * 8 + tt) * Hq + h] = acc[tt];

    if (hidx == 0) {
      if (tid == 0)
        for (int bb = 0; bb < Bq; bb++)
          while (__hip_atomic_load(&sflag[bb], __ATOMIC_RELAXED, __HIP_MEMORY_SCOPE_AGENT) == 0u)
            __builtin_amdgcn_s_sleep(2);
      __syncthreads();
      float s = 0.f;
      for (int i = tid; i < Bq * Tq; i += 256) s += dmask[i];
#pragma unroll
      for (int off = 32; off; off >>= 1) s += __shfl_xor(s, off);
      int w = tid >> 6, ln = tid & 63;
      if (ln == 0) r4[w] = s;
      __syncthreads();
      if (tid == 0)
        out_loss[0] = __hip_atomic_load(lacc, __ATOMIC_RELAXED, __HIP_MEMORY_SCOPE_AGENT)
                      / (r4[0] + r4[1] + r4[2] + r4[3]);
    }
  }
}

extern "C" void kernel_launch(void* const* d_in, const int* in_sizes, int n_in,
                              void* d_out, int out_size, void* d_ws, size_t ws_size,
                              hipStream_t stream) {
  const float* dec   = (const float*)d_in[0];   // [8,64,768]
  const float* dmask = (const float*)d_in[1];   // [8,64]
  const float* enc   = (const float*)d_in[2];   // [8,256,768]
  const float* emask = (const float*)d_in[3];   // [8,256]
  const float* cov0  = (const float*)d_in[4];   // [8,256]
  const float* Wh    = (const float*)d_in[5];   // [768,768]
  const float* Wd    = (const float*)d_in[6];   // [768,768]
  const float* bd    = (const float*)d_in[7];   // [768]
  const float* wc    = (const float*)d_in[8];   // [768]
  const float* vv    = (const float*)d_in[9];   // [768]
  float* out = (float*)d_out;

  char* ws = (char*)d_ws;
  __bf16*   efh   = (__bf16*)ws;                 // 3145728 B
  __bf16*   decfh = (__bf16*)(ws + 3145728);     // 786432 B
  float2*   ab    = (float2*)(ws + 3932160);     // 1048576 B
  float*    w1g   = (float*)(ws + 4980736);      // 3072 B
  float*    lacc  = (float*)(ws + 4983808);      // 4 B
  unsigned* cnt   = (unsigned*)(ws + 4983872);   // 32 B (64B-aligned)
  unsigned* sflag = (unsigned*)(ws + 4983936);   // 32 B

  const size_t OFF_ATTN = (size_t)Bq * Tq * Hq;             // 393216
  const size_t OFF_LOSS = OFF_ATTN + (size_t)Bq * Tq * Sq;  // 524288
  const size_t OFF_COV  = OFF_LOSS + 1;                     // 524289

  proj_kernel<<<480, 256, 0, stream>>>(enc, dec, Wh, Wd, bd, wc, vv,
                                       efh, decfh, w1g, lacc, cnt, sflag);
  tail_kernel<<<1024, 256, 0, stream>>>(efh, decfh, vv, w1g, emask, cov0,
                                        dmask, enc, ab,
                                        out + OFF_ATTN, out + OFF_COV,
                                        out, out + OFF_LOSS, lacc, cnt, sflag);
}

// Round 23
// 100.665 us; speedup vs baseline: 2.1646x; 1.0660x over previous
//
#include <hip/hip_runtime.h>

#define Bq 8
#define Tq 64
#define Sq 256
#define Hq 768
#define TT 8
#define ST 16

typedef float f32x4 __attribute__((ext_vector_type(4)));
typedef __bf16 bf16x8 __attribute__((ext_vector_type(8)));

#define TANH_SCALE 2.885390081777927f   // 2*log2(e): exp2(u*TS) = e^{2u}
#define LOG2E 1.4426950408889634f

// ---- DPP wave reduction -----------------------------------------------------
template <int Ctrl, int Rmask>
__device__ __forceinline__ float dpp_add_f(float v) {
  int t = __builtin_amdgcn_update_dpp(0, __float_as_int(v), Ctrl, Rmask, 0xF, true);
  return v + __int_as_float(t);
}
__device__ __forceinline__ float wave64_sum(float v) {
  v = dpp_add_f<0xB1, 0xF>(v);
  v = dpp_add_f<0x4E, 0xF>(v);
  v = dpp_add_f<0x141, 0xF>(v);
  v = dpp_add_f<0x140, 0xF>(v);
  v = dpp_add_f<0x142, 0xA>(v);
  v = dpp_add_f<0x143, 0xC>(v);
  return __int_as_float(__builtin_amdgcn_readlane(__float_as_int(v), 63));
}

__device__ __forceinline__ uint2 cvt4(f32x4 v) {
  union { __bf16 h[4]; uint2 u; } t;
  t.h[0] = (__bf16)v[0]; t.h[1] = (__bf16)v[1];
  t.h[2] = (__bf16)v[2]; t.h[3] = (__bf16)v[3];
  return t.u;
}

// ---------------- projection GEMMs (32x64 tiles, 960 blocks, high TLP) --------
// LDS-staged double-buffered, bf16 converted at stage. Row pad 40 shorts:
// 16B-aligned b128 fragment reads, <=2-way banks. Outputs PRE-EXPONENTIATED
// E=exp2(TS*ef), D=exp2(TS*dec) as bf16. Side duty: w1g + flags/lacc zero.
__global__ __launch_bounds__(256, 4) void proj_kernel(
    const float* __restrict__ enc, const float* __restrict__ dec,
    const float* __restrict__ Wh, const float* __restrict__ Wd,
    const float* __restrict__ bd,
    const float* __restrict__ wcvec, const float* __restrict__ vvec,
    __bf16* __restrict__ efh, __bf16* __restrict__ decfh,
    float* __restrict__ w1g, float* __restrict__ lacc,
    unsigned* __restrict__ sflag, unsigned* __restrict__ chunkflag)
{
  {
    int gidx = blockIdx.x * 256 + threadIdx.x;
    if (gidx < Hq) w1g[gidx] = vvec[gidx] * wcvec[gidx];
    if (gidx < 64) chunkflag[gidx] = 0u;
    if (gidx < Bq) sflag[gidx] = 0u;
    if (gidx == 0) lacc[0] = 0.f;
  }

  __shared__ unsigned short As[2][32][40];
  __shared__ unsigned short Bs[2][64][40];

  int bid = blockIdx.x;
  const float* A; const float* W; bool isEf;
  int bm, bn;
  if (bid < 768) {
    A = enc; W = Wh; isEf = true;
    bm = bid % 64; bn = bid / 64;               // XCD affinity via bm%8
  } else {
    bid -= 768;
    A = dec; W = Wd; isEf = false;
    bm = bid % 16; bn = bid / 16;
  }
  const int m0 = bm * 32, n0 = bn * 64;

  const int ti = threadIdx.x;
  const int rowA = ti >> 3, colA = (ti & 7) * 4;   // A: 32x32, 4 f32/thread
  const int rowB = ti >> 2, colB = (ti & 3) * 8;   // B: 64x32, 8 f32/thread
  const float* pa = A + (size_t)(m0 + rowA) * Hq + colA;
  const float* pw = W + (size_t)(n0 + rowB) * Hq + colB;

  {
    f32x4 a0 = *(const f32x4*)pa;
    f32x4 w0 = *(const f32x4*)pw, w1 = *(const f32x4*)(pw + 4);
    *(uint2*)&As[0][rowA][colA]     = cvt4(a0);
    *(uint2*)&Bs[0][rowB][colB]     = cvt4(w0);
    *(uint2*)&Bs[0][rowB][colB + 4] = cvt4(w1);
  }
  __syncthreads();

  const int w = ti >> 6, ln = ti & 63;
  const int mh = (w >> 1) * 16, nh = (w & 1) * 32;
  const int rsel = ln & 15, kofe = (ln >> 4) * 8;

  f32x4 acc[2] = {};
  for (int k = 0; k < 24; k++) {
    f32x4 na, nw0, nw1;
    if (k < 23) {
      na  = *(const f32x4*)(pa + (k + 1) * 32);
      nw0 = *(const f32x4*)(pw + (k + 1) * 32);
      nw1 = *(const f32x4*)(pw + (k + 1) * 32 + 4);
    }
    const int cur = k & 1;
    bf16x8 af = *(const bf16x8*)&As[cur][mh + rsel][kofe];
    bf16x8 b0 = *(const bf16x8*)&Bs[cur][nh + rsel][kofe];
    bf16x8 b1 = *(const bf16x8*)&Bs[cur][nh + 16 + rsel][kofe];
    acc[0] = __builtin_amdgcn_mfma_f32_16x16x32_bf16(af, b0, acc[0], 0, 0, 0);
    acc[1] = __builtin_amdgcn_mfma_f32_16x16x32_bf16(af, b1, acc[1], 0, 0, 0);
    if (k < 23) {
      const int nxt = cur ^ 1;
      *(uint2*)&As[nxt][rowA][colA]     = cvt4(na);
      *(uint2*)&Bs[nxt][rowB][colB]     = cvt4(nw0);
      *(uint2*)&Bs[nxt][rowB][colB + 4] = cvt4(nw1);
      __syncthreads();
    }
  }

  const int col = ln & 15, rb = (ln >> 4) * 4;
#pragma unroll
  for (int tn = 0; tn < 2; tn++)
#pragma unroll
    for (int j = 0; j < 4; j++) {
      int r = m0 + mh + rb + j, c = n0 + nh + tn * 16 + col;
      float val = acc[tn][j];
      if (isEf) {
        efh[(size_t)r * Hq + c] =
            (__bf16)__builtin_amdgcn_exp2f(val * TANH_SCALE);
      } else {
        decfh[(size_t)r * Hq + c] =
            (__bf16)__builtin_amdgcn_exp2f((val + bd[c]) * TANH_SCALE);
      }
    }
}

// ---------------- AB precompute (r18-proven body) -----------------------------
// score_s(t; cov) ~= A + cov*B. e^{2u} = E_s * D_t (pre-exponentiated bf16).
// 1024 blocks = 8b x 8tt x 16st; 256 thr = 128 pairs x 2 h-halves.
__global__ __launch_bounds__(256, 4) void abcd_kernel(
    const __bf16* __restrict__ efh, const __bf16* __restrict__ decfh,
    const float* __restrict__ vvec, const float* __restrict__ w1g,
    float2* __restrict__ ab)
{
  __shared__ unsigned short efs[ST][780];
  __shared__ unsigned short dts[TT][776];
  __shared__ float part[128][2];
  const int b = blockIdx.x & 7;
  const int r = blockIdx.x >> 3;            // 0..127
  const int tt0 = (r & 7) * TT;
  const int st0 = (r >> 3) * ST;
  const int tid = threadIdx.x;

  for (int i = tid; i < ST * 192; i += 256) {
    int row = i / 192, c = (i % 192) * 4;
    *(uint2*)&efs[row][c] =
        *(const uint2*)(efh + (size_t)(b * Sq + st0 + row) * Hq + c);
  }
  for (int i = tid; i < TT * 192; i += 256) {
    int row = i / 192, c = (i % 192) * 4;
    *(uint2*)&dts[row][c] =
        *(const uint2*)(decfh + (size_t)(b * Tq + tt0 + row) * Hq + c);
  }
  __syncthreads();

  const int hh = tid >> 7;
  const int pid = tid & 127;
  const int tl = pid >> 4, sl = pid & 15;
  const int hbase = hh * 384;
  const int hbu = __builtin_amdgcn_readfirstlane(hbase);
  const float* vp  = vvec + hbu;
  const float* w1p = w1g + hbu;

  float A = 0.f, B = 0.f;
#define BLO(x) __uint_as_float((x) << 16)
#define BHI(x) __uint_as_float((x) & 0xFFFF0000u)
#pragma unroll 4
  for (int j = 0; j < 384; j += 4) {
    uint2 eu = *(const uint2*)&efs[sl][hbase + j];
    uint2 du = *(const uint2*)&dts[tl][hbase + j];
    f32x4 v4 = *(const f32x4*)(vp + j);
    f32x4 w1 = *(const f32x4*)(w1p + j);
    float e2[4];
    e2[0] = BLO(eu.x) * BLO(du.x);
    e2[1] = BHI(eu.x) * BHI(du.x);
    e2[2] = BLO(eu.y) * BLO(du.y);
    e2[3] = BHI(eu.y) * BHI(du.y);
#pragma unroll
    for (int e = 0; e < 4; e++) {
      float rr = __builtin_amdgcn_rcpf(1.f + e2[e]);
      float t0 = 1.f - 2.f * rr;
      float f1 = 1.f - t0 * t0;
      A += v4[e] * t0;
      B += w1[e] * f1;
    }
  }
#undef BLO
#undef BHI

  if (hh == 1) { part[pid][0] = A; part[pid][1] = B; }
  __syncthreads();
  if (hh == 0) {
    float2 outv;
    outv.x = A + part[pid][0];
    outv.y = B + part[pid][1];
    ab[(size_t)(b * Tq + tt0 + tl) * Sq + st0 + sl] = outv;
  }
}

// ---------------- fused scan + ht with progressive chunk flags ---------------
// 200 blocks (8 scan + 192 ht). ab ready via stream order (no entry spin).
// Scan sets chunkflag[b][k] after steps 8k..8k+7 are drained (next iter's
// pre-barrier vmcnt(0)); ht block (b,tc) waits only on its own chunk ->
// ht overlaps most of the scan. attn handoff: relaxed agent atomics (IC).
__global__ __launch_bounds__(256, 2) void tail2_kernel(
    const float2* __restrict__ ab, const float* __restrict__ emask,
    const float* __restrict__ cov0, const float* __restrict__ dmask,
    const float* __restrict__ enc,
    float* __restrict__ out_attn, float* __restrict__ out_covf,
    float* __restrict__ out_ht, float* __restrict__ out_loss,
    float* __restrict__ lacc,
    unsigned* __restrict__ sflag, unsigned* __restrict__ chunkflag)
{
  __shared__ float smem[2180];
  const int bid = blockIdx.x;
  const int tid = threadIdx.x;

  if (bid < 8) {
    // -------- scan (batch b) --------
    float* zp   = smem;          // [2][4]
    float* dms  = smem + 8;      // [64]
    float* lred = smem + 72;     // [4]
    const int b = bid;
    const int s = tid, w = tid >> 6, ln = tid & 63;
    if (tid < Tq) dms[tid] = dmask[b * Tq + tid];
    const float em = emask[b * Sq + s];
    float cov = cov0[b * Sq + s];
    float lp = 0.f;
    const float2* P = ab + (size_t)b * Tq * Sq + s;
    float2 cur = P[0];
    __syncthreads();

    for (int t = 0; t < Tq; t++) {
      float2 nxt = (t + 1 < Tq) ? P[(size_t)(t + 1) * Sq] : cur;
      float sc = cur.x + cov * cur.y;
      float E = __builtin_amdgcn_exp2f(sc * LOG2E) * em;
      float wsum = wave64_sum(E);
      if (ln == 0) zp[(t & 1) * 4 + w] = wsum;
      __syncthreads();   // pre-barrier vmcnt(0) drains attn stores of steps < t
      if (tid == 0 && t >= 8 && (t & 7) == 0)
        __hip_atomic_store(&chunkflag[b * 8 + (t >> 3) - 1], 1u,
                           __ATOMIC_RELAXED, __HIP_MEMORY_SCOPE_AGENT);
      float Z = zp[(t & 1) * 4 + 0] + zp[(t & 1) * 4 + 1] +
                zp[(t & 1) * 4 + 2] + zp[(t & 1) * 4 + 3];
      float at = E * __builtin_amdgcn_rcpf(Z);
      lp += fminf(at, cov) * dms[t];
      cov += at;
      __hip_atomic_store(&out_attn[(size_t)(b * Tq + t) * Sq + s], at,
                         __ATOMIC_RELAXED, __HIP_MEMORY_SCOPE_AGENT);
      cur = nxt;
    }

    out_covf[b * Sq + s] = cov;             // host-only consumer
    float wl = wave64_sum(lp);
    if (ln == 0) lred[w] = wl;
    __syncthreads();                        // drains final chunk's attn stores
    if (tid == 0) {
      __hip_atomic_store(&chunkflag[b * 8 + 7], 1u,
                         __ATOMIC_RELAXED, __HIP_MEMORY_SCOPE_AGENT);
      atomicAdd(lacc, lred[0] + lred[1] + lred[2] + lred[3]);
      asm volatile("s_waitcnt vmcnt(0)" ::: "memory");
      __hip_atomic_store(&sflag[b], 1u,
                         __ATOMIC_RELAXED, __HIP_MEMORY_SCOPE_AGENT);
    }
  } else {
    // -------- ht tile --------
    float (*lat)[8] = (float(*)[8])smem;    // [256][8]
    float* r4 = smem + 2048;
    const int hidx = bid - 8;               // 0..191
    const int b = hidx / 24, r2 = hidx % 24, tc = r2 / 3, hc = r2 % 3;
    if (tid == 0)
      while (__hip_atomic_load(&chunkflag[b * 8 + tc],
                               __ATOMIC_RELAXED, __HIP_MEMORY_SCOPE_AGENT) == 0u)
        __builtin_amdgcn_s_sleep(2);
    __syncthreads();

    const int h = hc * 256 + tid;
#pragma unroll
    for (int tt = 0; tt < 8; tt++)
      lat[tid][tt] = __hip_atomic_load(
          &out_attn[(size_t)(b * Tq + tc * 8 + tt) * Sq + tid],
          __ATOMIC_RELAXED, __HIP_MEMORY_SCOPE_AGENT);
    __syncthreads();

    float acc[8] = {};
    const float* ep = enc + (size_t)(b * Sq) * Hq + h;
    for (int sb = 0; sb < Sq; sb += 8) {
      float e[8];
#pragma unroll
      for (int u = 0; u < 8; u++) e[u] = ep[(size_t)(sb + u) * Hq];
#pragma unroll
      for (int u = 0; u < 8; u++) {
        f32x4 a0 = *(const f32x4*)&lat[sb + u][0];
        f32x4 a1 = *(const f32x4*)&lat[sb + u][4];
        acc[0] += a0[0] * e[u]; acc[1] += a0[1] * e[u];
        acc[2] += a0[2] * e[u]; acc[3] += a0[3] * e[u];
        acc[4] += a1[0] * e[u]; acc[5] += a1[1] * e[u];
        acc[6] += a1[2] * e[u]; acc[7] += a1[3] * e[u];
      }
    }
#pragma unroll
    for (int tt = 0; tt < 8; tt++)
      out_ht[(size_t)(b * Tq + tc * 8 + tt) * Hq + h] = acc[tt];

    if (hidx == 0) {
      if (tid == 0)
        for (int bb = 0; bb < Bq; bb++)
          while (__hip_atomic_load(&sflag[bb],
                                   __ATOMIC_RELAXED, __HIP_MEMORY_SCOPE_AGENT) == 0u)
            __builtin_amdgcn_s_sleep(2);
      __syncthreads();
      float ssum = 0.f;
      for (int i = tid; i < Bq * Tq; i += 256) ssum += dmask[i];
#pragma unroll
      for (int off = 32; off; off >>= 1) ssum += __shfl_xor(ssum, off);
      int w = tid >> 6, ln = tid & 63;
      if (ln == 0) r4[w] = ssum;
      __syncthreads();
      if (tid == 0)
        out_loss[0] = __hip_atomic_load(lacc, __ATOMIC_RELAXED,
                                        __HIP_MEMORY_SCOPE_AGENT)
                      / (r4[0] + r4[1] + r4[2] + r4[3]);
    }
  }
}

extern "C" void kernel_launch(void* const* d_in, const int* in_sizes, int n_in,
                              void* d_out, int out_size, void* d_ws, size_t ws_size,
                              hipStream_t stream) {
  const float* dec   = (const float*)d_in[0];   // [8,64,768]
  const float* dmask = (const float*)d_in[1];   // [8,64]
  const float* enc   = (const float*)d_in[2];   // [8,256,768]
  const float* emask = (const float*)d_in[3];   // [8,256]
  const float* cov0  = (const float*)d_in[4];   // [8,256]
  const float* Wh    = (const float*)d_in[5];   // [768,768]
  const float* Wd    = (const float*)d_in[6];   // [768,768]
  const float* bd    = (const float*)d_in[7];   // [768]
  const float* wc    = (const float*)d_in[8];   // [768]
  const float* vv    = (const float*)d_in[9];   // [768]
  float* out = (float*)d_out;

  char* ws = (char*)d_ws;
  __bf16*   efh   = (__bf16*)ws;                 // 3145728 B
  __bf16*   decfh = (__bf16*)(ws + 3145728);     // 786432 B
  float2*   ab    = (float2*)(ws + 3932160);     // 1048576 B
  float*    w1g   = (float*)(ws + 4980736);      // 3072 B
  float*    lacc  = (float*)(ws + 4983808);      // 4 B
  unsigned* sflag = (unsigned*)(ws + 4983872);   // 32 B
  unsigned* chunkflag = (unsigned*)(ws + 4983936); // 256 B

  const size_t OFF_ATTN = (size_t)Bq * Tq * Hq;             // 393216
  const size_t OFF_LOSS = OFF_ATTN + (size_t)Bq * Tq * Sq;  // 524288
  const size_t OFF_COV  = OFF_LOSS + 1;                     // 524289

  proj_kernel<<<960, 256, 0, stream>>>(enc, dec, Wh, Wd, bd, wc, vv,
                                       efh, decfh, w1g, lacc, sflag, chunkflag);
  abcd_kernel<<<1024, 256, 0, stream>>>(efh, decfh, vv, w1g, ab);
  tail2_kernel<<<200, 256, 0, stream>>>(ab, emask, cov0, dmask, enc,
                                        out + OFF_ATTN, out + OFF_COV,
                                        out, out + OFF_LOSS, lacc,
                                        sflag, chunkflag);
}

// Round 24
// 90.919 us; speedup vs baseline: 2.3966x; 1.1072x over previous
//
#include <hip/hip_runtime.h>

#define Bq 8
#define Tq 64
#define Sq 256
#define Hq 768
#define TT 8
#define ST 16

typedef float f32x4 __attribute__((ext_vector_type(4)));
typedef __bf16 bf16x8 __attribute__((ext_vector_type(8)));

#define TANH_SCALE 2.885390081777927f   // 2*log2(e): exp2(u*TS) = e^{2u}
#define LOG2E 1.4426950408889634f

// ---- DPP wave reduction -----------------------------------------------------
template <int Ctrl, int Rmask>
__device__ __forceinline__ float dpp_add_f(float v) {
  int t = __builtin_amdgcn_update_dpp(0, __float_as_int(v), Ctrl, Rmask, 0xF, true);
  return v + __int_as_float(t);
}
__device__ __forceinline__ float wave64_sum(float v) {
  v = dpp_add_f<0xB1, 0xF>(v);
  v = dpp_add_f<0x4E, 0xF>(v);
  v = dpp_add_f<0x141, 0xF>(v);
  v = dpp_add_f<0x140, 0xF>(v);
  v = dpp_add_f<0x142, 0xA>(v);
  v = dpp_add_f<0x143, 0xC>(v);
  return __int_as_float(__builtin_amdgcn_readlane(__float_as_int(v), 63));
}

__device__ __forceinline__ uint2 cvt4(f32x4 v) {
  union { __bf16 h[4]; uint2 u; } t;
  t.h[0] = (__bf16)v[0]; t.h[1] = (__bf16)v[1];
  t.h[2] = (__bf16)v[2]; t.h[3] = (__bf16)v[3];
  return t.u;
}

// ---------------- projection GEMMs (32x64 tiles, 960 blocks, high TLP) --------
// r23-proven (~12us). LDS-staged double-buffered, bf16 at stage, pad 40.
// Outputs PRE-EXPONENTIATED E=exp2(TS*ef), D=exp2(TS*dec) as bf16.
__global__ __launch_bounds__(256, 4) void proj_kernel(
    const float* __restrict__ enc, const float* __restrict__ dec,
    const float* __restrict__ Wh, const float* __restrict__ Wd,
    const float* __restrict__ bd,
    const float* __restrict__ wcvec, const float* __restrict__ vvec,
    __bf16* __restrict__ efh, __bf16* __restrict__ decfh,
    float* __restrict__ w1g, float* __restrict__ lacc)
{
  {
    int gidx = blockIdx.x * 256 + threadIdx.x;
    if (gidx < Hq) w1g[gidx] = vvec[gidx] * wcvec[gidx];
    if (gidx == 0) lacc[0] = 0.f;
  }

  __shared__ unsigned short As[2][32][40];
  __shared__ unsigned short Bs[2][64][40];

  int bid = blockIdx.x;
  const float* A; const float* W; bool isEf;
  int bm, bn;
  if (bid < 768) {
    A = enc; W = Wh; isEf = true;
    bm = bid % 64; bn = bid / 64;               // XCD affinity via bm%8
  } else {
    bid -= 768;
    A = dec; W = Wd; isEf = false;
    bm = bid % 16; bn = bid / 16;
  }
  const int m0 = bm * 32, n0 = bn * 64;

  const int ti = threadIdx.x;
  const int rowA = ti >> 3, colA = (ti & 7) * 4;   // A: 32x32, 4 f32/thread
  const int rowB = ti >> 2, colB = (ti & 3) * 8;   // B: 64x32, 8 f32/thread
  const float* pa = A + (size_t)(m0 + rowA) * Hq + colA;
  const float* pw = W + (size_t)(n0 + rowB) * Hq + colB;

  {
    f32x4 a0 = *(const f32x4*)pa;
    f32x4 w0 = *(const f32x4*)pw, w1 = *(const f32x4*)(pw + 4);
    *(uint2*)&As[0][rowA][colA]     = cvt4(a0);
    *(uint2*)&Bs[0][rowB][colB]     = cvt4(w0);
    *(uint2*)&Bs[0][rowB][colB + 4] = cvt4(w1);
  }
  __syncthreads();

  const int w = ti >> 6, ln = ti & 63;
  const int mh = (w >> 1) * 16, nh = (w & 1) * 32;
  const int rsel = ln & 15, kofe = (ln >> 4) * 8;

  f32x4 acc[2] = {};
  for (int k = 0; k < 24; k++) {
    f32x4 na, nw0, nw1;
    if (k < 23) {
      na  = *(const f32x4*)(pa + (k + 1) * 32);
      nw0 = *(const f32x4*)(pw + (k + 1) * 32);
      nw1 = *(const f32x4*)(pw + (k + 1) * 32 + 4);
    }
    const int cur = k & 1;
    bf16x8 af = *(const bf16x8*)&As[cur][mh + rsel][kofe];
    bf16x8 b0 = *(const bf16x8*)&Bs[cur][nh + rsel][kofe];
    bf16x8 b1 = *(const bf16x8*)&Bs[cur][nh + 16 + rsel][kofe];
    acc[0] = __builtin_amdgcn_mfma_f32_16x16x32_bf16(af, b0, acc[0], 0, 0, 0);
    acc[1] = __builtin_amdgcn_mfma_f32_16x16x32_bf16(af, b1, acc[1], 0, 0, 0);
    if (k < 23) {
      const int nxt = cur ^ 1;
      *(uint2*)&As[nxt][rowA][colA]     = cvt4(na);
      *(uint2*)&Bs[nxt][rowB][colB]     = cvt4(nw0);
      *(uint2*)&Bs[nxt][rowB][colB + 4] = cvt4(nw1);
      __syncthreads();
    }
  }

  const int col = ln & 15, rb = (ln >> 4) * 4;
#pragma unroll
  for (int tn = 0; tn < 2; tn++)
#pragma unroll
    for (int j = 0; j < 4; j++) {
      int r = m0 + mh + rb + j, c = n0 + nh + tn * 16 + col;
      float val = acc[tn][j];
      if (isEf) {
        efh[(size_t)r * Hq + c] =
            (__bf16)__builtin_amdgcn_exp2f(val * TANH_SCALE);
      } else {
        decfh[(size_t)r * Hq + c] =
            (__bf16)__builtin_amdgcn_exp2f((val + bd[c]) * TANH_SCALE);
      }
    }
}

// ---------------- AB precompute (r18-proven, ~33us) ---------------------------
// score_s(t; cov) ~= A + cov*B. e^{2u} = E_s * D_t (pre-exponentiated bf16).
__global__ __launch_bounds__(256, 4) void abcd_kernel(
    const __bf16* __restrict__ efh, const __bf16* __restrict__ decfh,
    const float* __restrict__ vvec, const float* __restrict__ w1g,
    float2* __restrict__ ab)
{
  __shared__ unsigned short efs[ST][780];
  __shared__ unsigned short dts[TT][776];
  __shared__ float part[128][2];
  const int b = blockIdx.x & 7;
  const int r = blockIdx.x >> 3;            // 0..127
  const int tt0 = (r & 7) * TT;
  const int st0 = (r >> 3) * ST;
  const int tid = threadIdx.x;

  for (int i = tid; i < ST * 192; i += 256) {
    int row = i / 192, c = (i % 192) * 4;
    *(uint2*)&efs[row][c] =
        *(const uint2*)(efh + (size_t)(b * Sq + st0 + row) * Hq + c);
  }
  for (int i = tid; i < TT * 192; i += 256) {
    int row = i / 192, c = (i % 192) * 4;
    *(uint2*)&dts[row][c] =
        *(const uint2*)(decfh + (size_t)(b * Tq + tt0 + row) * Hq + c);
  }
  __syncthreads();

  const int hh = tid >> 7;
  const int pid = tid & 127;
  const int tl = pid >> 4, sl = pid & 15;
  const int hbase = hh * 384;
  const int hbu = __builtin_amdgcn_readfirstlane(hbase);
  const float* vp  = vvec + hbu;
  const float* w1p = w1g + hbu;

  float A = 0.f, B = 0.f;
#define BLO(x) __uint_as_float((x) << 16)
#define BHI(x) __uint_as_float((x) & 0xFFFF0000u)
#pragma unroll 4
  for (int j = 0; j < 384; j += 4) {
    uint2 eu = *(const uint2*)&efs[sl][hbase + j];
    uint2 du = *(const uint2*)&dts[tl][hbase + j];
    f32x4 v4 = *(const f32x4*)(vp + j);
    f32x4 w1 = *(const f32x4*)(w1p + j);
    float e2[4];
    e2[0] = BLO(eu.x) * BLO(du.x);
    e2[1] = BHI(eu.x) * BHI(du.x);
    e2[2] = BLO(eu.y) * BLO(du.y);
    e2[3] = BHI(eu.y) * BHI(du.y);
#pragma unroll
    for (int e = 0; e < 4; e++) {
      float rr = __builtin_amdgcn_rcpf(1.f + e2[e]);
      float t0 = 1.f - 2.f * rr;
      float f1 = 1.f - t0 * t0;
      A += v4[e] * t0;
      B += w1[e] * f1;
    }
  }
#undef BLO
#undef BHI

  if (hh == 1) { part[pid][0] = A; part[pid][1] = B; }
  __syncthreads();
  if (hh == 0) {
    float2 outv;
    outv.x = A + part[pid][0];
    outv.y = B + part[pid][1];
    ab[(size_t)(b * Tq + tt0 + tl) * Sq + st0 + sl] = outv;
  }
}

// ---------------- scan: one batch = one 256-thread block (r18-proven) ---------
__global__ __launch_bounds__(256, 1) void scan2_kernel(
    const float2* __restrict__ ab, const float* __restrict__ emask,
    const float* __restrict__ cov0, const float* __restrict__ dmask,
    float* __restrict__ out_attn, float* __restrict__ out_covf,
    float* __restrict__ lacc)
{
  __shared__ float zp[2][4];
  __shared__ float dms[Tq];
  __shared__ float lred[4];
  const int b = blockIdx.x;
  const int s = threadIdx.x;
  const int w = s >> 6, ln = s & 63;
  if (s < Tq) dms[s] = dmask[b * Tq + s];
  const float em = emask[b * Sq + s];
  float cov = cov0[b * Sq + s];
  float lp = 0.f;
  const float2* P = ab + (size_t)b * Tq * Sq + s;
  float2 cur = P[0];
  __syncthreads();

  for (int t = 0; t < Tq; t++) {
    float2 nxt = (t + 1 < Tq) ? P[(size_t)(t + 1) * Sq] : cur;  // prefetch
    float sc = cur.x + cov * cur.y;
    float E = __builtin_amdgcn_exp2f(sc * LOG2E) * em;
    float wsum = wave64_sum(E);
    if (ln == 0) zp[t & 1][w] = wsum;
    __syncthreads();
    float Z = zp[t & 1][0] + zp[t & 1][1] + zp[t & 1][2] + zp[t & 1][3];
    float at = E * __builtin_amdgcn_rcpf(Z);
    lp += fminf(at, cov) * dms[t];
    cov += at;
    out_attn[(size_t)(b * Tq + t) * Sq + s] = at;
    cur = nxt;
  }

  out_covf[b * Sq + s] = cov;
  float wl = wave64_sum(lp);
  if (ln == 0) lred[w] = wl;
  __syncthreads();
  if (s == 0) atomicAdd(lacc, lred[0] + lred[1] + lred[2] + lred[3]);
}

// ---------------- deferred ht = attn @ enc + loss finalize (r18-proven) -------
__global__ __launch_bounds__(256) void ht_kernel(
    const float* __restrict__ attn, const float* __restrict__ enc,
    const float* __restrict__ dmask, const float* __restrict__ lacc,
    float* __restrict__ out_ht, float* __restrict__ out_loss)
{
  __shared__ float lat[Sq][8];
  __shared__ float r4[4];
  int bid = blockIdx.x;
  int b = bid / 24, r = bid % 24, tc = r / 3, hc = r % 3;
  int tid = threadIdx.x;
  int h = hc * 256 + tid;
#pragma unroll
  for (int tt = 0; tt < 8; tt++)
    lat[tid][tt] = attn[(size_t)(b * Tq + tc * 8 + tt) * Sq + tid];
  __syncthreads();

  float acc[8] = {};
  const float* ep = enc + (size_t)(b * Sq) * Hq + h;
  for (int sb = 0; sb < Sq; sb += 8) {
    float e[8];
#pragma unroll
    for (int u = 0; u < 8; u++) e[u] = ep[(size_t)(sb + u) * Hq];
#pragma unroll
    for (int u = 0; u < 8; u++) {
      f32x4 a0 = *(const f32x4*)&lat[sb + u][0];
      f32x4 a1 = *(const f32x4*)&lat[sb + u][4];
      acc[0] += a0[0] * e[u]; acc[1] += a0[1] * e[u];
      acc[2] += a0[2] * e[u]; acc[3] += a0[3] * e[u];
      acc[4] += a1[0] * e[u]; acc[5] += a1[1] * e[u];
      acc[6] += a1[2] * e[u]; acc[7] += a1[3] * e[u];
    }
  }
#pragma unroll
  for (int tt = 0; tt < 8; tt++)
    out_ht[(size_t)(b * Tq + tc * 8 + tt) * Hq + h] = acc[tt];

  if (blockIdx.x == 0) {
    float s = 0.f;
    for (int i = tid; i < Bq * Tq; i += 256) s += dmask[i];
#pragma unroll
    for (int off = 32; off; off >>= 1) s += __shfl_xor(s, off);
    int w = tid >> 6, ln = tid & 63;
    if (ln == 0) r4[w] = s;
    __syncthreads();
    if (tid == 0) out_loss[0] = lacc[0] / (r4[0] + r4[1] + r4[2] + r4[3]);
  }
}

extern "C" void kernel_launch(void* const* d_in, const int* in_sizes, int n_in,
                              void* d_out, int out_size, void* d_ws, size_t ws_size,
                              hipStream_t stream) {
  const float* dec   = (const float*)d_in[0];   // [8,64,768]
  const float* dmask = (const float*)d_in[1];   // [8,64]
  const float* enc   = (const float*)d_in[2];   // [8,256,768]
  const float* emask = (const float*)d_in[3];   // [8,256]
  const float* cov0  = (const float*)d_in[4];   // [8,256]
  const float* Wh    = (const float*)d_in[5];   // [768,768]
  const float* Wd    = (const float*)d_in[6];   // [768,768]
  const float* bd    = (const float*)d_in[7];   // [768]
  const float* wc    = (const float*)d_in[8];   // [768]
  const float* vv    = (const float*)d_in[9];   // [768]
  float* out = (float*)d_out;

  char* ws = (char*)d_ws;
  __bf16* efh   = (__bf16*)ws;                   // 3145728 B
  __bf16* decfh = (__bf16*)(ws + 3145728);       // 786432 B
  float2* ab    = (float2*)(ws + 3932160);       // 1048576 B
  float*  w1g   = (float*)(ws + 4980736);        // 3072 B
  float*  lacc  = (float*)(ws + 4983808);        // 4 B

  const size_t OFF_ATTN = (size_t)Bq * Tq * Hq;             // 393216
  const size_t OFF_LOSS = OFF_ATTN + (size_t)Bq * Tq * Sq;  // 524288
  const size_t OFF_COV  = OFF_LOSS + 1;                     // 524289

  proj_kernel<<<960, 256, 0, stream>>>(enc, dec, Wh, Wd, bd, wc, vv,
                                       efh, decfh, w1g, lacc);
  abcd_kernel<<<1024, 256, 0, stream>>>(efh, decfh, vv, w1g, ab);
  scan2_kernel<<<Bq, 256, 0, stream>>>(ab, emask, cov0, dmask,
                                       out + OFF_ATTN, out + OFF_COV, lacc);
  ht_kernel<<<192, 256, 0, stream>>>(out + OFF_ATTN, enc, dmask, lacc,
                                     out, out + OFF_LOSS);
}

// Round 25
// 84.936 us; speedup vs baseline: 2.5655x; 1.0704x over previous
//
#include <hip/hip_runtime.h>

#define Bq 8
#define Tq 64
#define Sq 256
#define Hq 768
#define TT 8
#define ST 16

typedef float f32x4 __attribute__((ext_vector_type(4)));
typedef __bf16 bf16x8 __attribute__((ext_vector_type(8)));

#define TANH_SCALE 2.885390081777927f   // 2*log2(e): exp2(u*TS) = e^{2u}
#define LOG2E 1.4426950408889634f

// ---- DPP wave reduction -----------------------------------------------------
template <int Ctrl, int Rmask>
__device__ __forceinline__ float dpp_add_f(float v) {
  int t = __builtin_amdgcn_update_dpp(0, __float_as_int(v), Ctrl, Rmask, 0xF, true);
  return v + __int_as_float(t);
}
__device__ __forceinline__ float wave64_sum(float v) {
  v = dpp_add_f<0xB1, 0xF>(v);
  v = dpp_add_f<0x4E, 0xF>(v);
  v = dpp_add_f<0x141, 0xF>(v);
  v = dpp_add_f<0x140, 0xF>(v);
  v = dpp_add_f<0x142, 0xA>(v);
  v = dpp_add_f<0x143, 0xC>(v);
  return __int_as_float(__builtin_amdgcn_readlane(__float_as_int(v), 63));
}

__device__ __forceinline__ uint2 cvt4(f32x4 v) {
  union { __bf16 h[4]; uint2 u; } t;
  t.h[0] = (__bf16)v[0]; t.h[1] = (__bf16)v[1];
  t.h[2] = (__bf16)v[2]; t.h[3] = (__bf16)v[3];
  return t.u;
}

// ---------------- projection GEMMs (32x64 tiles, 960 blocks, high TLP) --------
// r23-proven (~12us). LDS-staged double-buffered, bf16 at stage, pad 40.
// Outputs PRE-EXPONENTIATED E=exp2(TS*ef), D=exp2(TS*dec) as bf16.
// Side duty: w1g, zero lacc + 64 chunk counters.
__global__ __launch_bounds__(256, 4) void proj_kernel(
    const float* __restrict__ enc, const float* __restrict__ dec,
    const float* __restrict__ Wh, const float* __restrict__ Wd,
    const float* __restrict__ bd,
    const float* __restrict__ wcvec, const float* __restrict__ vvec,
    __bf16* __restrict__ efh, __bf16* __restrict__ decfh,
    float* __restrict__ w1g, float* __restrict__ lacc,
    unsigned* __restrict__ cnt)
{
  {
    int gidx = blockIdx.x * 256 + threadIdx.x;
    if (gidx < Hq) w1g[gidx] = vvec[gidx] * wcvec[gidx];
    if (gidx < 64) cnt[gidx] = 0u;
    if (gidx == 0) lacc[0] = 0.f;
  }

  __shared__ unsigned short As[2][32][40];
  __shared__ unsigned short Bs[2][64][40];

  int bid = blockIdx.x;
  const float* A; const float* W; bool isEf;
  int bm, bn;
  if (bid < 768) {
    A = enc; W = Wh; isEf = true;
    bm = bid % 64; bn = bid / 64;               // XCD affinity via bm%8
  } else {
    bid -= 768;
    A = dec; W = Wd; isEf = false;
    bm = bid % 16; bn = bid / 16;
  }
  const int m0 = bm * 32, n0 = bn * 64;

  const int ti = threadIdx.x;
  const int rowA = ti >> 3, colA = (ti & 7) * 4;   // A: 32x32, 4 f32/thread
  const int rowB = ti >> 2, colB = (ti & 3) * 8;   // B: 64x32, 8 f32/thread
  const float* pa = A + (size_t)(m0 + rowA) * Hq + colA;
  const float* pw = W + (size_t)(n0 + rowB) * Hq + colB;

  {
    f32x4 a0 = *(const f32x4*)pa;
    f32x4 w0 = *(const f32x4*)pw, w1 = *(const f32x4*)(pw + 4);
    *(uint2*)&As[0][rowA][colA]     = cvt4(a0);
    *(uint2*)&Bs[0][rowB][colB]     = cvt4(w0);
    *(uint2*)&Bs[0][rowB][colB + 4] = cvt4(w1);
  }
  __syncthreads();

  const int w = ti >> 6, ln = ti & 63;
  const int mh = (w >> 1) * 16, nh = (w & 1) * 32;
  const int rsel = ln & 15, kofe = (ln >> 4) * 8;

  f32x4 acc[2] = {};
  for (int k = 0; k < 24; k++) {
    f32x4 na, nw0, nw1;
    if (k < 23) {
      na  = *(const f32x4*)(pa + (k + 1) * 32);
      nw0 = *(const f32x4*)(pw + (k + 1) * 32);
      nw1 = *(const f32x4*)(pw + (k + 1) * 32 + 4);
    }
    const int cur = k & 1;
    bf16x8 af = *(const bf16x8*)&As[cur][mh + rsel][kofe];
    bf16x8 b0 = *(const bf16x8*)&Bs[cur][nh + rsel][kofe];
    bf16x8 b1 = *(const bf16x8*)&Bs[cur][nh + 16 + rsel][kofe];
    acc[0] = __builtin_amdgcn_mfma_f32_16x16x32_bf16(af, b0, acc[0], 0, 0, 0);
    acc[1] = __builtin_amdgcn_mfma_f32_16x16x32_bf16(af, b1, acc[1], 0, 0, 0);
    if (k < 23) {
      const int nxt = cur ^ 1;
      *(uint2*)&As[nxt][rowA][colA]     = cvt4(na);
      *(uint2*)&Bs[nxt][rowB][colB]     = cvt4(nw0);
      *(uint2*)&Bs[nxt][rowB][colB + 4] = cvt4(nw1);
      __syncthreads();
    }
  }

  const int col = ln & 15, rb = (ln >> 4) * 4;
#pragma unroll
  for (int tn = 0; tn < 2; tn++)
#pragma unroll
    for (int j = 0; j < 4; j++) {
      int r = m0 + mh + rb + j, c = n0 + nh + tn * 16 + col;
      float val = acc[tn][j];
      if (isEf) {
        efh[(size_t)r * Hq + c] =
            (__bf16)__builtin_amdgcn_exp2f(val * TANH_SCALE);
      } else {
        decfh[(size_t)r * Hq + c] =
            (__bf16)__builtin_amdgcn_exp2f((val + bd[c]) * TANH_SCALE);
      }
    }
}

// ---------------- fused AB + scan --------------------------------------------
// 1032 blocks: 0..1023 = AB tiles (r18-proven body; ab stored ONCE at end via
// relaxed agent u64 -> IC, drained by the pre-cnt barrier), 1024..1031 = scan
// (one per batch). Dependency is one-directional -> deadlock-free under any
// dispatch order. Scan waits per 8-step chunk on cnt[b*8+k]==16, reads ab via
// relaxed agent loads (8-deep prefetch), writes attn with PLAIN cached stores
// (consumer ht is a separate stream-ordered kernel; kernel-end flush).
__global__ __launch_bounds__(256, 4) void abscan_kernel(
    const __bf16* __restrict__ efh, const __bf16* __restrict__ decfh,
    const float* __restrict__ vvec, const float* __restrict__ w1g,
    const float* __restrict__ emask, const float* __restrict__ cov0,
    const float* __restrict__ dmask,
    float2* __restrict__ ab,
    float* __restrict__ out_attn, float* __restrict__ out_covf,
    float* __restrict__ lacc, unsigned* __restrict__ cnt)
{
  __shared__ double smem_raw[4808];           // 38464 B
  const int bid = blockIdx.x;
  const int tid = threadIdx.x;

  if (bid < 1024) {
    // -------- AB tile --------
    unsigned short (*efs)[780] = (unsigned short(*)[780])smem_raw;
    unsigned short (*dts)[776] = (unsigned short(*)[776])((char*)smem_raw + 24960);
    float (*part)[2]           = (float(*)[2])((char*)smem_raw + 37376);
    const int b = bid & 7;
    const int r = bid >> 3;                   // 0..127
    const int kchunk = r & 7;                 // t-chunk 0..7
    const int tt0 = kchunk * TT;
    const int st0 = (r >> 3) * ST;

    for (int i = tid; i < ST * 192; i += 256) {
      int row = i / 192, c = (i % 192) * 4;
      *(uint2*)&efs[row][c] =
          *(const uint2*)(efh + (size_t)(b * Sq + st0 + row) * Hq + c);
    }
    for (int i = tid; i < TT * 192; i += 256) {
      int row = i / 192, c = (i % 192) * 4;
      *(uint2*)&dts[row][c] =
          *(const uint2*)(decfh + (size_t)(b * Tq + tt0 + row) * Hq + c);
    }
    __syncthreads();

    const int hh = tid >> 7;
    const int pid = tid & 127;
    const int tl = pid >> 4, sl = pid & 15;
    const int hbase = hh * 384;
    const int hbu = __builtin_amdgcn_readfirstlane(hbase);
    const float* vp  = vvec + hbu;
    const float* w1p = w1g + hbu;

    float A = 0.f, B = 0.f;
#define BLO(x) __uint_as_float((x) << 16)
#define BHI(x) __uint_as_float((x) & 0xFFFF0000u)
#pragma unroll 4
    for (int j = 0; j < 384; j += 4) {
      uint2 eu = *(const uint2*)&efs[sl][hbase + j];
      uint2 du = *(const uint2*)&dts[tl][hbase + j];
      f32x4 v4 = *(const f32x4*)(vp + j);
      f32x4 w1 = *(const f32x4*)(w1p + j);
      float e2[4];
      e2[0] = BLO(eu.x) * BLO(du.x);
      e2[1] = BHI(eu.x) * BHI(du.x);
      e2[2] = BLO(eu.y) * BLO(du.y);
      e2[3] = BHI(eu.y) * BHI(du.y);
#pragma unroll
      for (int e = 0; e < 4; e++) {
        float rr = __builtin_amdgcn_rcpf(1.f + e2[e]);
        float t0 = 1.f - 2.f * rr;
        float f1 = 1.f - t0 * t0;
        A += v4[e] * t0;
        B += w1[e] * f1;
      }
    }
#undef BLO
#undef BHI

    if (hh == 1) { part[pid][0] = A; part[pid][1] = B; }
    __syncthreads();
    if (hh == 0) {
      union { float2 f; unsigned long long u; } cv;
      cv.f.x = A + part[pid][0];
      cv.f.y = B + part[pid][1];
      __hip_atomic_store(
          (unsigned long long*)&ab[(size_t)(b * Tq + tt0 + tl) * Sq + st0 + sl],
          cv.u, __ATOMIC_RELAXED, __HIP_MEMORY_SCOPE_AGENT);
    }
    __syncthreads();   // drains all waves' ab stores (vmcnt(0) pre-barrier)
    if (tid == 0)
      __hip_atomic_fetch_add(&cnt[b * 8 + kchunk], 1u,
                             __ATOMIC_RELAXED, __HIP_MEMORY_SCOPE_AGENT);
  } else {
    // -------- scan (batch b), chunked behind cnt flags --------
    float* zp   = (float*)smem_raw;           // [2][4]
    float* dms  = (float*)smem_raw + 8;       // [64]
    float* lred = (float*)smem_raw + 72;      // [4]
    const int b = bid - 1024;
    const int s = tid, w = tid >> 6, ln = tid & 63;
    if (tid < Tq) dms[tid] = dmask[b * Tq + tid];
    const float em = emask[b * Sq + s];
    float cov = cov0[b * Sq + s];
    float lp = 0.f;
    const unsigned long long* P =
        (const unsigned long long*)(ab + (size_t)b * Tq * Sq + s);

    for (int kc = 0; kc < 8; kc++) {
      if (tid == 0)
        while (__hip_atomic_load(&cnt[b * 8 + kc],
                                 __ATOMIC_RELAXED, __HIP_MEMORY_SCOPE_AGENT) < 16u)
          __builtin_amdgcn_s_sleep(2);
      __syncthreads();                        // releases block when chunk ready

      union { unsigned long long u; float2 f; } cv[8];
#pragma unroll
      for (int j = 0; j < 8; j++)             // 8-deep prefetch of the chunk
        cv[j].u = __hip_atomic_load(P + (size_t)(kc * 8 + j) * Sq,
                                    __ATOMIC_RELAXED, __HIP_MEMORY_SCOPE_AGENT);

#pragma unroll
      for (int j = 0; j < 8; j++) {
        const int t = kc * 8 + j;
        float sc = cv[j].f.x + cov * cv[j].f.y;
        float E = __builtin_amdgcn_exp2f(sc * LOG2E) * em;
        float wsum = wave64_sum(E);
        if (ln == 0) zp[(t & 1) * 4 + w] = wsum;
        __syncthreads();
        float Z = zp[(t & 1) * 4 + 0] + zp[(t & 1) * 4 + 1] +
                  zp[(t & 1) * 4 + 2] + zp[(t & 1) * 4 + 3];
        float at = E * __builtin_amdgcn_rcpf(Z);
        lp += fminf(at, cov) * dms[t];
        cov += at;
        out_attn[(size_t)(b * Tq + t) * Sq + s] = at;   // plain cached store
      }
    }

    out_covf[b * Sq + s] = cov;
    float wl = wave64_sum(lp);
    if (ln == 0) lred[w] = wl;
    __syncthreads();
    if (tid == 0) atomicAdd(lacc, lred[0] + lred[1] + lred[2] + lred[3]);
  }
}

// ---------------- deferred ht = attn @ enc + loss finalize (r18-proven) -------
__global__ __launch_bounds__(256) void ht_kernel(
    const float* __restrict__ attn, const float* __restrict__ enc,
    const float* __restrict__ dmask, const float* __restrict__ lacc,
    float* __restrict__ out_ht, float* __restrict__ out_loss)
{
  __shared__ float lat[Sq][8];
  __shared__ float r4[4];
  int bid = blockIdx.x;
  int b = bid / 24, r = bid % 24, tc = r / 3, hc = r % 3;
  int tid = threadIdx.x;
  int h = hc * 256 + tid;
#pragma unroll
  for (int tt = 0; tt < 8; tt++)
    lat[tid][tt] = attn[(size_t)(b * Tq + tc * 8 + tt) * Sq + tid];
  __syncthreads();

  float acc[8] = {};
  const float* ep = enc + (size_t)(b * Sq) * Hq + h;
  for (int sb = 0; sb < Sq; sb += 8) {
    float e[8];
#pragma unroll
    for (int u = 0; u < 8; u++) e[u] = ep[(size_t)(sb + u) * Hq];
#pragma unroll
    for (int u = 0; u < 8; u++) {
      f32x4 a0 = *(const f32x4*)&lat[sb + u][0];
      f32x4 a1 = *(const f32x4*)&lat[sb + u][4];
      acc[0] += a0[0] * e[u]; acc[1] += a0[1] * e[u];
      acc[2] += a0[2] * e[u]; acc[3] += a0[3] * e[u];
      acc[4] += a1[0] * e[u]; acc[5] += a1[1] * e[u];
      acc[6] += a1[2] * e[u]; acc[7] += a1[3] * e[u];
    }
  }
#pragma unroll
  for (int tt = 0; tt < 8; tt++)
    out_ht[(size_t)(b * Tq + tc * 8 + tt) * Hq + h] = acc[tt];

  if (blockIdx.x == 0) {
    float s = 0.f;
    for (int i = tid; i < Bq * Tq; i += 256) s += dmask[i];
#pragma unroll
    for (int off = 32; off; off >>= 1) s += __shfl_xor(s, off);
    int w = tid >> 6, ln = tid & 63;
    if (ln == 0) r4[w] = s;
    __syncthreads();
    if (tid == 0) out_loss[0] = lacc[0] / (r4[0] + r4[1] + r4[2] + r4[3]);
  }
}

extern "C" void kernel_launch(void* const* d_in, const int* in_sizes, int n_in,
                              void* d_out, int out_size, void* d_ws, size_t ws_size,
                              hipStream_t stream) {
  const float* dec   = (const float*)d_in[0];   // [8,64,768]
  const float* dmask = (const float*)d_in[1];   // [8,64]
  const float* enc   = (const float*)d_in[2];   // [8,256,768]
  const float* emask = (const float*)d_in[3];   // [8,256]
  const float* cov0  = (const float*)d_in[4];   // [8,256]
  const float* Wh    = (const float*)d_in[5];   // [768,768]
  const float* Wd    = (const float*)d_in[6];   // [768,768]
  const float* bd    = (const float*)d_in[7];   // [768]
  const float* wc    = (const float*)d_in[8];   // [768]
  const float* vv    = (const float*)d_in[9];   // [768]
  float* out = (float*)d_out;

  char* ws = (char*)d_ws;
  __bf16*   efh   = (__bf16*)ws;                 // 3145728 B
  __bf16*   decfh = (__bf16*)(ws + 3145728);     // 786432 B
  float2*   ab    = (float2*)(ws + 3932160);     // 1048576 B
  float*    w1g   = (float*)(ws + 4980736);      // 3072 B
  float*    lacc  = (float*)(ws + 4983808);      // 4 B
  unsigned* cnt   = (unsigned*)(ws + 4983872);   // 256 B

  const size_t OFF_ATTN = (size_t)Bq * Tq * Hq;             // 393216
  const size_t OFF_LOSS = OFF_ATTN + (size_t)Bq * Tq * Sq;  // 524288
  const size_t OFF_COV  = OFF_LOSS + 1;                     // 524289

  proj_kernel<<<960, 256, 0, stream>>>(enc, dec, Wh, Wd, bd, wc, vv,
                                       efh, decfh, w1g, lacc, cnt);
  abscan_kernel<<<1032, 256, 0, stream>>>(efh, decfh, vv, w1g, emask, cov0,
                                          dmask, ab,
                                          out + OFF_ATTN, out + OFF_COV,
                                          lacc, cnt);
  ht_kernel<<<192, 256, 0, stream>>>(out + OFF_ATTN, enc, dmask, lacc,
                                     out, out + OFF_LOSS);
}

// Round 26
// 80.254 us; speedup vs baseline: 2.7151x; 1.0583x over previous
//
#include <hip/hip_runtime.h>

#define Bq 8
#define Tq 64
#define Sq 256
#define Hq 768
#define TT 8
#define ST 16

typedef float f32x4 __attribute__((ext_vector_type(4)));
typedef __bf16 bf16x8 __attribute__((ext_vector_type(8)));

#define TANH_SCALE 2.885390081777927f   // 2*log2(e): exp2(u*TS) = e^{2u}
#define LOG2E 1.4426950408889634f

// ---- DPP reduction -----------------------------------------------------------
template <int Ctrl, int Rmask>
__device__ __forceinline__ float dpp_add_f(float v) {
  int t = __builtin_amdgcn_update_dpp(0, __float_as_int(v), Ctrl, Rmask, 0xF, true);
  return v + __int_as_float(t);
}
__device__ __forceinline__ float wave64_sum(float v) {
  v = dpp_add_f<0xB1, 0xF>(v);
  v = dpp_add_f<0x4E, 0xF>(v);
  v = dpp_add_f<0x141, 0xF>(v);
  v = dpp_add_f<0x140, 0xF>(v);
  v = dpp_add_f<0x142, 0xA>(v);
  v = dpp_add_f<0x143, 0xC>(v);
  return __int_as_float(__builtin_amdgcn_readlane(__float_as_int(v), 63));
}

__device__ __forceinline__ uint2 cvt4(f32x4 v) {
  union { __bf16 h[4]; uint2 u; } t;
  t.h[0] = (__bf16)v[0]; t.h[1] = (__bf16)v[1];
  t.h[2] = (__bf16)v[2]; t.h[3] = (__bf16)v[3];
  return t.u;
}

// ---------------- projection GEMMs (r23-proven, ~12us) ------------------------
__global__ __launch_bounds__(256, 4) void proj_kernel(
    const float* __restrict__ enc, const float* __restrict__ dec,
    const float* __restrict__ Wh, const float* __restrict__ Wd,
    const float* __restrict__ bd,
    const float* __restrict__ wcvec, const float* __restrict__ vvec,
    __bf16* __restrict__ efh, __bf16* __restrict__ decfh,
    float* __restrict__ w1g, float* __restrict__ lacc,
    unsigned* __restrict__ cnt)
{
  {
    int gidx = blockIdx.x * 256 + threadIdx.x;
    if (gidx < Hq) w1g[gidx] = vvec[gidx] * wcvec[gidx];
    if (gidx < 64) cnt[gidx] = 0u;
    if (gidx == 0) lacc[0] = 0.f;
  }

  __shared__ unsigned short As[2][32][40];
  __shared__ unsigned short Bs[2][64][40];

  int bid = blockIdx.x;
  const float* A; const float* W; bool isEf;
  int bm, bn;
  if (bid < 768) {
    A = enc; W = Wh; isEf = true;
    bm = bid % 64; bn = bid / 64;               // XCD affinity via bm%8
  } else {
    bid -= 768;
    A = dec; W = Wd; isEf = false;
    bm = bid % 16; bn = bid / 16;
  }
  const int m0 = bm * 32, n0 = bn * 64;

  const int ti = threadIdx.x;
  const int rowA = ti >> 3, colA = (ti & 7) * 4;
  const int rowB = ti >> 2, colB = (ti & 3) * 8;
  const float* pa = A + (size_t)(m0 + rowA) * Hq + colA;
  const float* pw = W + (size_t)(n0 + rowB) * Hq + colB;

  {
    f32x4 a0 = *(const f32x4*)pa;
    f32x4 w0 = *(const f32x4*)pw, w1 = *(const f32x4*)(pw + 4);
    *(uint2*)&As[0][rowA][colA]     = cvt4(a0);
    *(uint2*)&Bs[0][rowB][colB]     = cvt4(w0);
    *(uint2*)&Bs[0][rowB][colB + 4] = cvt4(w1);
  }
  __syncthreads();

  const int w = ti >> 6, ln = ti & 63;
  const int mh = (w >> 1) * 16, nh = (w & 1) * 32;
  const int rsel = ln & 15, kofe = (ln >> 4) * 8;

  f32x4 acc[2] = {};
  for (int k = 0; k < 24; k++) {
    f32x4 na, nw0, nw1;
    if (k < 23) {
      na  = *(const f32x4*)(pa + (k + 1) * 32);
      nw0 = *(const f32x4*)(pw + (k + 1) * 32);
      nw1 = *(const f32x4*)(pw + (k + 1) * 32 + 4);
    }
    const int cur = k & 1;
    bf16x8 af = *(const bf16x8*)&As[cur][mh + rsel][kofe];
    bf16x8 b0 = *(const bf16x8*)&Bs[cur][nh + rsel][kofe];
    bf16x8 b1 = *(const bf16x8*)&Bs[cur][nh + 16 + rsel][kofe];
    acc[0] = __builtin_amdgcn_mfma_f32_16x16x32_bf16(af, b0, acc[0], 0, 0, 0);
    acc[1] = __builtin_amdgcn_mfma_f32_16x16x32_bf16(af, b1, acc[1], 0, 0, 0);
    if (k < 23) {
      const int nxt = cur ^ 1;
      *(uint2*)&As[nxt][rowA][colA]     = cvt4(na);
      *(uint2*)&Bs[nxt][rowB][colB]     = cvt4(nw0);
      *(uint2*)&Bs[nxt][rowB][colB + 4] = cvt4(nw1);
      __syncthreads();
    }
  }

  const int col = ln & 15, rb = (ln >> 4) * 4;
#pragma unroll
  for (int tn = 0; tn < 2; tn++)
#pragma unroll
    for (int j = 0; j < 4; j++) {
      int r = m0 + mh + rb + j, c = n0 + nh + tn * 16 + col;
      float val = acc[tn][j];
      if (isEf) {
        efh[(size_t)r * Hq + c] =
            (__bf16)__builtin_amdgcn_exp2f(val * TANH_SCALE);
      } else {
        decfh[(size_t)r * Hq + c] =
            (__bf16)__builtin_amdgcn_exp2f((val + bd[c]) * TANH_SCALE);
      }
    }
}

// ---------------- fused AB + single-wave scan ---------------------------------
// 1032 blocks: 0..1023 = AB tiles (r25-proven), 1024..1031 = scan. Scan uses
// ONLY wave 0 (waves 1-3 return): lane owns 4 s-rows; per step 4 polys + 4
// exp2 + one DPP wave-sum + rcp — no __syncthreads, no LDS on critical path.
// Per-chunk wait on cnt[b*8+kc]==16 (relaxed, wave-local); 2-deep ab prefetch.
__global__ __launch_bounds__(256, 4) void abscan_kernel(
    const __bf16* __restrict__ efh, const __bf16* __restrict__ decfh,
    const float* __restrict__ vvec, const float* __restrict__ w1g,
    const float* __restrict__ emask, const float* __restrict__ cov0,
    const float* __restrict__ dmask,
    float2* __restrict__ ab,
    float* __restrict__ out_attn, float* __restrict__ out_covf,
    float* __restrict__ lacc, unsigned* __restrict__ cnt)
{
  __shared__ double smem_raw[4808];           // 38464 B
  const int bid = blockIdx.x;
  const int tid = threadIdx.x;

  if (bid < 1024) {
    // -------- AB tile (r25-proven) --------
    unsigned short (*efs)[780] = (unsigned short(*)[780])smem_raw;
    unsigned short (*dts)[776] = (unsigned short(*)[776])((char*)smem_raw + 24960);
    float (*part)[2]           = (float(*)[2])((char*)smem_raw + 37376);
    const int b = bid & 7;
    const int r = bid >> 3;                   // 0..127
    const int kchunk = r & 7;
    const int tt0 = kchunk * TT;
    const int st0 = (r >> 3) * ST;

    for (int i = tid; i < ST * 192; i += 256) {
      int row = i / 192, c = (i % 192) * 4;
      *(uint2*)&efs[row][c] =
          *(const uint2*)(efh + (size_t)(b * Sq + st0 + row) * Hq + c);
    }
    for (int i = tid; i < TT * 192; i += 256) {
      int row = i / 192, c = (i % 192) * 4;
      *(uint2*)&dts[row][c] =
          *(const uint2*)(decfh + (size_t)(b * Tq + tt0 + row) * Hq + c);
    }
    __syncthreads();

    const int hh = tid >> 7;
    const int pid = tid & 127;
    const int tl = pid >> 4, sl = pid & 15;
    const int hbase = hh * 384;
    const int hbu = __builtin_amdgcn_readfirstlane(hbase);
    const float* vp  = vvec + hbu;
    const float* w1p = w1g + hbu;

    float A = 0.f, B = 0.f;
#define BLO(x) __uint_as_float((x) << 16)
#define BHI(x) __uint_as_float((x) & 0xFFFF0000u)
#pragma unroll 4
    for (int j = 0; j < 384; j += 4) {
      uint2 eu = *(const uint2*)&efs[sl][hbase + j];
      uint2 du = *(const uint2*)&dts[tl][hbase + j];
      f32x4 v4 = *(const f32x4*)(vp + j);
      f32x4 w1 = *(const f32x4*)(w1p + j);
      float e2[4];
      e2[0] = BLO(eu.x) * BLO(du.x);
      e2[1] = BHI(eu.x) * BHI(du.x);
      e2[2] = BLO(eu.y) * BLO(du.y);
      e2[3] = BHI(eu.y) * BHI(du.y);
#pragma unroll
      for (int e = 0; e < 4; e++) {
        float rr = __builtin_amdgcn_rcpf(1.f + e2[e]);
        float t0 = 1.f - 2.f * rr;
        float f1 = 1.f - t0 * t0;
        A += v4[e] * t0;
        B += w1[e] * f1;
      }
    }
#undef BLO
#undef BHI

    if (hh == 1) { part[pid][0] = A; part[pid][1] = B; }
    __syncthreads();
    if (hh == 0) {
      union { float2 f; unsigned long long u; } cv;
      cv.f.x = A + part[pid][0];
      cv.f.y = B + part[pid][1];
      __hip_atomic_store(
          (unsigned long long*)&ab[(size_t)(b * Tq + tt0 + tl) * Sq + st0 + sl],
          cv.u, __ATOMIC_RELAXED, __HIP_MEMORY_SCOPE_AGENT);
    }
    __syncthreads();   // drains ab stores (vmcnt(0) pre-barrier)
    if (tid == 0)
      __hip_atomic_fetch_add(&cnt[b * 8 + kchunk], 1u,
                             __ATOMIC_RELAXED, __HIP_MEMORY_SCOPE_AGENT);
  } else {
    // -------- single-wave scan (batch b) --------
    if (tid >= 64) return;                    // waves 1-3 exit
    const int b = bid - 1024;
    const int ln = tid;
    float dm = dmask[b * Tq + ln];            // lane t holds dmask[b][t]
    float cov[4], em[4], E[4];
    float lp = 0.f;
#pragma unroll
    for (int i = 0; i < 4; i++) {
      cov[i] = cov0[b * Sq + ln + 64 * i];
      em[i]  = emask[b * Sq + ln + 64 * i];
    }
    const unsigned long long* P =
        (const unsigned long long*)(ab + (size_t)b * Tq * Sq + ln);
    union U64 { unsigned long long u; float2 f; };
    U64 cv0[4], cv1[4];                       // 2-deep prefetch

    for (int kc = 0; kc < 8; kc++) {
      unsigned c;
      do {
        c = __hip_atomic_load(&cnt[b * 8 + kc],
                              __ATOMIC_RELAXED, __HIP_MEMORY_SCOPE_AGENT);
      } while (__builtin_amdgcn_readfirstlane(c) < 16u);

      const int tb = kc * 8;
#pragma unroll
      for (int i = 0; i < 4; i++)
        cv0[i].u = __hip_atomic_load(P + (size_t)tb * Sq + 64 * i,
                                     __ATOMIC_RELAXED, __HIP_MEMORY_SCOPE_AGENT);
#pragma unroll
      for (int i = 0; i < 4; i++)
        cv1[i].u = __hip_atomic_load(P + (size_t)(tb + 1) * Sq + 64 * i,
                                     __ATOMIC_RELAXED, __HIP_MEMORY_SCOPE_AGENT);

#pragma unroll
      for (int j = 0; j < 8; j++) {
        const int t = tb + j;
        float s4 = 0.f;
#pragma unroll
        for (int i = 0; i < 4; i++) {
          float sc = cv0[i].f.x + cov[i] * cv0[i].f.y;
          E[i] = __builtin_amdgcn_exp2f(sc * LOG2E) * em[i];
          s4 += E[i];
        }
        // rotate prefetch: issue load for step t+2 before the reduction
#pragma unroll
        for (int i = 0; i < 4; i++) {
          cv0[i] = cv1[i];
          if (j < 6)
            cv1[i].u = __hip_atomic_load(P + (size_t)(t + 2) * Sq + 64 * i,
                                         __ATOMIC_RELAXED, __HIP_MEMORY_SCOPE_AGENT);
        }
        float Z = wave64_sum(s4);
        float invZ = __builtin_amdgcn_rcpf(Z);
        float dmt = __shfl(dm, t);
#pragma unroll
        for (int i = 0; i < 4; i++) {
          float at = E[i] * invZ;
          lp += fminf(at, cov[i]) * dmt;
          cov[i] += at;
          out_attn[(size_t)(b * Tq + t) * Sq + ln + 64 * i] = at;  // plain store
        }
      }
    }

#pragma unroll
    for (int i = 0; i < 4; i++)
      out_covf[b * Sq + ln + 64 * i] = cov[i];
    float wl = wave64_sum(lp);
    if (ln == 0) atomicAdd(lacc, wl);
  }
}

// ---------------- deferred ht = attn @ enc + loss finalize (r18-proven) -------
__global__ __launch_bounds__(256) void ht_kernel(
    const float* __restrict__ attn, const float* __restrict__ enc,
    const float* __restrict__ dmask, const float* __restrict__ lacc,
    float* __restrict__ out_ht, float* __restrict__ out_loss)
{
  __shared__ float lat[Sq][8];
  __shared__ float r4[4];
  int bid = blockIdx.x;
  int b = bid / 24, r = bid % 24, tc = r / 3, hc = r % 3;
  int tid = threadIdx.x;
  int h = hc * 256 + tid;
#pragma unroll
  for (int tt = 0; tt < 8; tt++)
    lat[tid][tt] = attn[(size_t)(b * Tq + tc * 8 + tt) * Sq + tid];
  __syncthreads();

  float acc[8] = {};
  const float* ep = enc + (size_t)(b * Sq) * Hq + h;
  for (int sb = 0; sb < Sq; sb += 8) {
    float e[8];
#pragma unroll
    for (int u = 0; u < 8; u++) e[u] = ep[(size_t)(sb + u) * Hq];
#pragma unroll
    for (int u = 0; u < 8; u++) {
      f32x4 a0 = *(const f32x4*)&lat[sb + u][0];
      f32x4 a1 = *(const f32x4*)&lat[sb + u][4];
      acc[0] += a0[0] * e[u]; acc[1] += a0[1] * e[u];
      acc[2] += a0[2] * e[u]; acc[3] += a0[3] * e[u];
      acc[4] += a1[0] * e[u]; acc[5] += a1[1] * e[u];
      acc[6] += a1[2] * e[u]; acc[7] += a1[3] * e[u];
    }
  }
#pragma unroll
  for (int tt = 0; tt < 8; tt++)
    out_ht[(size_t)(b * Tq + tc * 8 + tt) * Hq + h] = acc[tt];

  if (blockIdx.x == 0) {
    float s = 0.f;
    for (int i = tid; i < Bq * Tq; i += 256) s += dmask[i];
#pragma unroll
    for (int off = 32; off; off >>= 1) s += __shfl_xor(s, off);
    int w = tid >> 6, ln = tid & 63;
    if (ln == 0) r4[w] = s;
    __syncthreads();
    if (tid == 0) out_loss[0] = lacc[0] / (r4[0] + r4[1] + r4[2] + r4[3]);
  }
}

extern "C" void kernel_launch(void* const* d_in, const int* in_sizes, int n_in,
                              void* d_out, int out_size, void* d_ws, size_t ws_size,
                              hipStream_t stream) {
  const float* dec   = (const float*)d_in[0];   // [8,64,768]
  const float* dmask = (const float*)d_in[1];   // [8,64]
  const float* enc   = (const float*)d_in[2];   // [8,256,768]
  const float* emask = (const float*)d_in[3];   // [8,256]
  const float* cov0  = (const float*)d_in[4];   // [8,256]
  const float* Wh    = (const float*)d_in[5];   // [768,768]
  const float* Wd    = (const float*)d_in[6];   // [768,768]
  const float* bd    = (const float*)d_in[7];   // [768]
  const float* wc    = (const float*)d_in[8];   // [768]
  const float* vv    = (const float*)d_in[9];   // [768]
  float* out = (float*)d_out;

  char* ws = (char*)d_ws;
  __bf16*   efh   = (__bf16*)ws;                 // 3145728 B
  __bf16*   decfh = (__bf16*)(ws + 3145728);     // 786432 B
  float2*   ab    = (float2*)(ws + 3932160);     // 1048576 B
  float*    w1g   = (float*)(ws + 4980736);      // 3072 B
  float*    lacc  = (float*)(ws + 4983808);      // 4 B
  unsigned* cnt   = (unsigned*)(ws + 4983872);   // 256 B

  const size_t OFF_ATTN = (size_t)Bq * Tq * Hq;             // 393216
  const size_t OFF_LOSS = OFF_ATTN + (size_t)Bq * Tq * Sq;  // 524288
  const size_t OFF_COV  = OFF_LOSS + 1;                     // 524289

  proj_kernel<<<960, 256, 0, stream>>>(enc, dec, Wh, Wd, bd, wc, vv,
                                       efh, decfh, w1g, lacc, cnt);
  abscan_kernel<<<1032, 256, 0, stream>>>(efh, decfh, vv, w1g, emask, cov0,
                                          dmask, ab,
                                          out + OFF_ATTN, out + OFF_COV,
                                          lacc, cnt);
  ht_kernel<<<192, 256, 0, stream>>>(out + OFF_ATTN, enc, dmask, lacc,
                                     out, out + OFF_LOSS);
}